// Round 3
// baseline (3345.996 us; speedup 1.0000x reference)
//
#include <hip/hip_runtime.h>
#include <math.h>

#define B_    2
#define S_    2048
#define HID_  1024
#define H_    16
#define D_    64
#define KEEP_ 204
#define QT_   8

// order-preserving fp32 -> uint32 mapping (larger float <=> larger uint)
__device__ __forceinline__ unsigned f2u_ord(float x) {
    unsigned b = __float_as_uint(x);
    return (b & 0x80000000u) ? ~b : (b | 0x80000000u);
}
__device__ __forceinline__ float u2f_ord(unsigned u) {
    unsigned b = (u & 0x80000000u) ? (u ^ 0x80000000u) : ~u;
    return __uint_as_float(b);
}
__device__ __forceinline__ float wave_sum(float x) {
    #pragma unroll
    for (int off = 32; off > 0; off >>= 1) x += __shfl_xor(x, off);
    return x;
}
__device__ __forceinline__ float wave_max(float x) {
    #pragma unroll
    for (int off = 32; off > 0; off >>= 1) x = fmaxf(x, __shfl_xor(x, off));
    return x;
}

// ---------------- GEMM: Y = A @ W + bias ----------------
template <int MODE>
__global__ __launch_bounds__(256) void gemm_f32_k(
    const float* __restrict__ A, const float* __restrict__ W,
    const float* __restrict__ bias, float* __restrict__ Y,
    int M, int N, int Kd)
{
    __shared__ __align__(16) float As[16][64];
    __shared__ __align__(16) float Bs[16][64];
    const int tid = threadIdx.x;
    const int tx = tid & 15, ty = tid >> 4;
    const int n0 = blockIdx.x * 64, m0 = blockIdx.y * 64;
    float acc[4][4] = {};
    for (int k0 = 0; k0 < Kd; k0 += 16) {
        {
            const int c4 = tid & 3, r = tid >> 2;
            const float4 a4 = *(const float4*)&A[(m0 + r) * Kd + k0 + c4 * 4];
            As[c4*4+0][r] = a4.x; As[c4*4+1][r] = a4.y;
            As[c4*4+2][r] = a4.z; As[c4*4+3][r] = a4.w;
        }
        {
            const int r4 = tid & 15, c = tid >> 4;
            *(float4*)&Bs[c][r4*4] = *(const float4*)&W[(k0 + c) * N + n0 + r4*4];
        }
        __syncthreads();
        #pragma unroll
        for (int kk = 0; kk < 16; kk++) {
            const float4 a4 = *(const float4*)&As[kk][ty*4];
            const float4 b4 = *(const float4*)&Bs[kk][tx*4];
            const float av[4] = {a4.x, a4.y, a4.z, a4.w};
            const float bv[4] = {b4.x, b4.y, b4.z, b4.w};
            #pragma unroll
            for (int i = 0; i < 4; i++)
                #pragma unroll
                for (int j = 0; j < 4; j++)
                    acc[i][j] = fmaf(av[i], bv[j], acc[i][j]);
        }
        __syncthreads();
    }
    if (MODE == 0) {
        #pragma unroll
        for (int i = 0; i < 4; i++) {
            const int m = m0 + ty*4 + i;
            float4 o;
            o.x = acc[i][0] + bias[n0+tx*4+0];
            o.y = acc[i][1] + bias[n0+tx*4+1];
            o.z = acc[i][2] + bias[n0+tx*4+2];
            o.w = acc[i][3] + bias[n0+tx*4+3];
            *(float4*)&Y[m * N + n0 + tx*4] = o;
        }
    } else {
        #pragma unroll
        for (int i = 0; i < 4; i++) {
            const int m = m0 + ty*4 + i;
            const int b = m >> 11, s = m & (S_ - 1);
            #pragma unroll
            for (int j = 0; j < 4; j++) {
                const int n = n0 + tx*4 + j;
                const int h = n >> 6, d = n & 63;
                Y[((b * H_ + h) * S_ + s) * D_ + d] = acc[i][j] + bias[n];
            }
        }
    }
}

// ---------------- sumV[bh][d] = sum_j V[bh][j][d] ----------------
__global__ __launch_bounds__(256) void sumv_k(const float* __restrict__ V,
                                              float* __restrict__ sumV)
{
    const int bh = blockIdx.x;
    const int d = threadIdx.x & 63;
    const int g = threadIdx.x >> 6;
    float acc = 0.f;
    for (int j = g; j < S_; j += 4)
        acc += V[(bh * S_ + j) * D_ + d];
    __shared__ float part[4][D_];
    part[g][d] = acc;
    __syncthreads();
    if (threadIdx.x < 64)
        sumV[bh * D_ + d] = part[0][d] + part[1][d] + part[2][d] + part[3][d];
}

// ---------------- fused scores + exact top-204 + sparse-softmax AV ----------------
// 256 threads = 4 waves per block; cooperative scores, then each wave owns
// 2 query rows with ZERO block barriers (wave-private hist/list, shuffle
// reductions, ballot compaction).
// NOTE: plain __launch_bounds__(256) — the (256,2) variant made the allocator
// clamp to 128 VGPRs and spill ~4 GB of scratch per dispatch (R2 counters:
// WRITE_SIZE 2.6 GB vs 16 MB of real output). Occupancy is LDS-bound at
// 2 blocks/CU regardless, so the VGPR cap bought nothing.
__global__ __launch_bounds__(256) void attn_topk_k(
    const float* __restrict__ Q, const float* __restrict__ Kg,
    const float* __restrict__ V, const float* __restrict__ sumV,
    float* __restrict__ AO)
{
    const int tid = threadIdx.x;
    const int wv = tid >> 6;
    const int lane = tid & 63;
    const int bh = blockIdx.x >> 8;            // S_/QT_ = 256 q-tiles per (b,h)
    const int q0 = (blockIdx.x & 255) * QT_;
    const int b = bh >> 4, h = bh & (H_ - 1);

    __shared__ __align__(16) float sc[QT_][S_];      // 64 KB
    __shared__ __align__(16) float qs[QT_][D_];
    __shared__ __align__(16) unsigned hist[4][256];  // wave-private
    __shared__ __align__(16) int   list_j[4][224];   // wave-private
    __shared__ __align__(16) float list_w[4][224];

    for (int i = tid; i < QT_ * D_; i += 256)
        qs[i >> 6][i & 63] = Q[(bh * S_ + q0 + (i >> 6)) * D_ + (i & 63)];
    __syncthreads();

    // ---- cooperative scores: thread covers 4 q rows x 16 j's ----
    {
        const int qh = tid >> 7;
        const int jl = tid & 127;
        float acc[4][16];
        #pragma unroll
        for (int qq = 0; qq < 4; qq++)
            #pragma unroll
            for (int i = 0; i < 16; i++) acc[qq][i] = 0.f;
        #pragma unroll
        for (int db = 0; db < 4; db++) {
            float4 qv[4][4];
            #pragma unroll
            for (int qq = 0; qq < 4; qq++)
                #pragma unroll
                for (int dd = 0; dd < 4; dd++)
                    qv[qq][dd] = *(const float4*)&qs[qh*4+qq][db*16 + dd*4];
            for (int i = 0; i < 16; i++) {
                const float4* kp = (const float4*)&Kg[(bh * S_ + jl + 128*i) * D_];
                float4 kv[4];
                #pragma unroll
                for (int dd = 0; dd < 4; dd++) kv[dd] = kp[db*4 + dd];
                #pragma unroll
                for (int qq = 0; qq < 4; qq++) {
                    float s = 0.f;
                    #pragma unroll
                    for (int dd = 0; dd < 4; dd++) {
                        s = fmaf(kv[dd].x, qv[qq][dd].x, s);
                        s = fmaf(kv[dd].y, qv[qq][dd].y, s);
                        s = fmaf(kv[dd].z, qv[qq][dd].z, s);
                        s = fmaf(kv[dd].w, qv[qq][dd].w, s);
                    }
                    acc[qq][i] += s;
                }
            }
        }
        #pragma unroll
        for (int qq = 0; qq < 4; qq++)
            for (int i = 0; i < 16; i++)
                sc[qh*4+qq][jl + 128*i] = acc[qq][i] * 0.125f;
    }
    __syncthreads();

    const float* Vb = V + (size_t)bh * S_ * D_;

    for (int rr = 0; rr < 2; rr++) {
        const int qr = wv * 2 + rr;

        // row into registers: lane owns j = i*256 + lane*4 + k
        float4 v4[8];
        #pragma unroll
        for (int i = 0; i < 8; i++)
            v4[i] = *(const float4*)&sc[qr][i * 256 + lane * 4];

        float lm = -INFINITY;
        #pragma unroll
        for (int i = 0; i < 8; i++)
            lm = fmaxf(lm, fmaxf(fmaxf(v4[i].x, v4[i].y), fmaxf(v4[i].z, v4[i].w)));
        const float m = fmaxf(wave_max(lm), 0.0f);   // sparse row includes zeros

        // ---- exact radix select (wave-private, barrier-free) ----
        unsigned prefix = 0;
        int rem = KEEP_;
        #pragma unroll
        for (int pass = 3; pass >= 0; pass--) {
            const int shift = pass * 8;
            *(uint4*)&hist[wv][lane * 4] = make_uint4(0u, 0u, 0u, 0u);
            #pragma unroll
            for (int i = 0; i < 8; i++) {
                const float vv[4] = {v4[i].x, v4[i].y, v4[i].z, v4[i].w};
                #pragma unroll
                for (int k = 0; k < 4; k++) {
                    const unsigned u = f2u_ord(vv[k]);
                    const bool match = (pass == 3) ||
                        ((u >> (shift + 8)) == (prefix >> (shift + 8)));
                    if (match) atomicAdd(&hist[wv][(u >> shift) & 255u], 1u);
                }
            }
            const uint4 h4 = *(const uint4*)&hist[wv][lane * 4];
            const unsigned s3 = h4.w;
            const unsigned s2 = h4.z + s3;
            const unsigned s1 = h4.y + s2;
            const unsigned s0 = h4.x + s1;
            unsigned incl = s0;                       // suffix scan across lanes
            #pragma unroll
            for (int off = 1; off < 64; off <<= 1) {
                const unsigned t = __shfl_down(incl, off);
                if (lane + off < 64) incl += t;
            }
            const unsigned excl = incl - s0;
            const unsigned cge[4] = {excl + s0, excl + s1, excl + s2, excl + s3};
            const unsigned cgt[4] = {excl + s1, excl + s2, excl + s3, excl};
            unsigned pk = 0;
            bool found = false;
            #pragma unroll
            for (int k = 0; k < 4; k++) {
                if (cge[k] >= (unsigned)rem && cgt[k] < (unsigned)rem) {
                    found = true;
                    pk = ((unsigned)(lane * 4 + k) << 16) | cgt[k];
                }
            }
            const unsigned long long fm = __ballot(found);
            const int src = __builtin_ctzll(fm);
            pk = __shfl(pk, src);
            prefix |= (pk >> 16) << shift;
            rem -= (int)(pk & 0xffffu);
        }
        const unsigned T = prefix;
        const float expT = __expf(u2f_ord(T) - m);

        // ---- build list via ballot compaction (no atomics) ----
        float esum = 0.f;
        int base = 0;
        int eqTotal = 0;
        #pragma unroll
        for (int i = 0; i < 8; i++) {
            const float vv[4] = {v4[i].x, v4[i].y, v4[i].z, v4[i].w};
            #pragma unroll
            for (int k = 0; k < 4; k++) {
                const unsigned u = f2u_ord(vv[k]);
                const bool gt = u > T;
                const unsigned long long mg = __ballot(gt);
                if (gt) {
                    const int pos = base + (int)__popcll(mg & ((1ULL << lane) - 1ULL));
                    const float w = __expf(vv[k] - m);
                    list_j[wv][pos] = i * 256 + lane * 4 + k;
                    list_w[wv][pos] = w;
                    esum += w;
                }
                base += (int)__popcll(mg);
                eqTotal += (int)__popcll(__ballot(u == T));
            }
        }
        if (eqTotal == rem) {            // normal: take all ties
            #pragma unroll
            for (int i = 0; i < 8; i++) {
                const float vv[4] = {v4[i].x, v4[i].y, v4[i].z, v4[i].w};
                #pragma unroll
                for (int k = 0; k < 4; k++) {
                    const unsigned u = f2u_ord(vv[k]);
                    const bool eq = (u == T);
                    const unsigned long long mg = __ballot(eq);
                    if (eq) {
                        const int pos = base + (int)__popcll(mg & ((1ULL << lane) - 1ULL));
                        list_j[wv][pos] = i * 256 + lane * 4 + k;
                        list_w[wv][pos] = expT;
                    }
                    base += (int)__popcll(mg);
                }
            }
        } else if (lane == 0) {          // rare tie overflow: lowest-index order
            int p = base, need = rem;
            for (int j = 0; j < S_ && need > 0; j++) {
                if (f2u_ord(sc[qr][j]) == T) {
                    list_j[wv][p] = j; list_w[wv][p] = expT; p++; need--;
                }
            }
        }
        const float E = wave_sum(esum) + (float)rem * expT;

        __asm__ volatile("s_waitcnt lgkmcnt(0)" ::: "memory");

        // ---- AV gather: lane = d, loop over 204 selected (51 x 4) ----
        float accW = 0.f, accS = 0.f;
        #pragma unroll 1
        for (int p = 0; p < KEEP_; p += 4) {
            const int4   j4 = *(const int4*)&list_j[wv][p];
            const float4 w4 = *(const float4*)&list_w[wv][p];
            const float a0 = Vb[j4.x * 64 + lane];
            const float a1 = Vb[j4.y * 64 + lane];
            const float a2 = Vb[j4.z * 64 + lane];
            const float a3 = Vb[j4.w * 64 + lane];
            accW = fmaf(w4.x, a0, accW);
            accW = fmaf(w4.y, a1, accW);
            accW = fmaf(w4.z, a2, accW);
            accW = fmaf(w4.w, a3, accW);
            accS += a0 + a1 + a2 + a3;
        }
        const float em = __expf(-m);
        const float denom = E + (float)(S_ - KEEP_) * em;
        const float numer = accW + em * (sumV[bh * D_ + lane] - accS);
        AO[(b * S_ + q0 + qr) * HID_ + h * D_ + lane] = numer / denom;
    }
}

extern "C" void kernel_launch(void* const* d_in, const int* in_sizes, int n_in,
                              void* d_out, int out_size, void* d_ws, size_t ws_size,
                              hipStream_t stream) {
    const float* x  = (const float*)d_in[0];
    const float* Wq = (const float*)d_in[1];
    const float* bq = (const float*)d_in[2];
    const float* Wk = (const float*)d_in[3];
    const float* bk = (const float*)d_in[4];
    const float* Wv = (const float*)d_in[5];
    const float* bv = (const float*)d_in[6];
    const float* Wo = (const float*)d_in[7];
    const float* bo = (const float*)d_in[8];
    float* out = (float*)d_out;

    float* ws = (float*)d_ws;
    const size_t NQ = (size_t)B_ * H_ * S_ * D_;
    float* Qw = ws;
    float* Kw = ws + NQ;
    float* Vw = ws + 2 * NQ;
    float* AO = ws + 3 * NQ;
    float* sV = ws + 4 * NQ;

    dim3 blk(256);
    dim3 gg(HID_ / 64, (B_ * S_) / 64);
    gemm_f32_k<1><<<gg, blk, 0, stream>>>(x, Wq, bq, Qw, B_ * S_, HID_, HID_);
    gemm_f32_k<1><<<gg, blk, 0, stream>>>(x, Wk, bk, Kw, B_ * S_, HID_, HID_);
    gemm_f32_k<1><<<gg, blk, 0, stream>>>(x, Wv, bv, Vw, B_ * S_, HID_, HID_);
    sumv_k<<<dim3(B_ * H_), blk, 0, stream>>>(Vw, sV);
    attn_topk_k<<<dim3(B_ * H_ * (S_ / QT_)), blk, 0, stream>>>(Qw, Kw, Vw, sV, AO);
    gemm_f32_k<0><<<gg, blk, 0, stream>>>(AO, Wo, bo, out, B_ * S_, HID_, HID_);
}

// Round 4
// 2900.564 us; speedup vs baseline: 1.1536x; 1.1536x over previous
//
#include <hip/hip_runtime.h>
#include <math.h>

#define B_    2
#define S_    2048
#define HID_  1024
#define H_    16
#define D_    64
#define KEEP_ 204
#define QT_   8

// order-preserving fp32 -> uint32 mapping (larger float <=> larger uint)
__device__ __forceinline__ unsigned f2u_ord(float x) {
    unsigned b = __float_as_uint(x);
    return (b & 0x80000000u) ? ~b : (b | 0x80000000u);
}
__device__ __forceinline__ float u2f_ord(unsigned u) {
    unsigned b = (u & 0x80000000u) ? (u ^ 0x80000000u) : ~u;
    return __uint_as_float(b);
}
__device__ __forceinline__ float wave_sum(float x) {
    #pragma unroll
    for (int off = 32; off > 0; off >>= 1) x += __shfl_xor(x, off);
    return x;
}
__device__ __forceinline__ float wave_max(float x) {
    #pragma unroll
    for (int off = 32; off > 0; off >>= 1) x = fmaxf(x, __shfl_xor(x, off));
    return x;
}

// ---------------- GEMM: Y = A @ W + bias ----------------
template <int MODE>
__global__ __launch_bounds__(256) void gemm_f32_k(
    const float* __restrict__ A, const float* __restrict__ W,
    const float* __restrict__ bias, float* __restrict__ Y,
    int M, int N, int Kd)
{
    __shared__ __align__(16) float As[16][64];
    __shared__ __align__(16) float Bs[16][64];
    const int tid = threadIdx.x;
    const int tx = tid & 15, ty = tid >> 4;
    const int n0 = blockIdx.x * 64, m0 = blockIdx.y * 64;
    float acc[4][4] = {};
    for (int k0 = 0; k0 < Kd; k0 += 16) {
        {
            const int c4 = tid & 3, r = tid >> 2;
            const float4 a4 = *(const float4*)&A[(m0 + r) * Kd + k0 + c4 * 4];
            As[c4*4+0][r] = a4.x; As[c4*4+1][r] = a4.y;
            As[c4*4+2][r] = a4.z; As[c4*4+3][r] = a4.w;
        }
        {
            const int r4 = tid & 15, c = tid >> 4;
            *(float4*)&Bs[c][r4*4] = *(const float4*)&W[(k0 + c) * N + n0 + r4*4];
        }
        __syncthreads();
        #pragma unroll
        for (int kk = 0; kk < 16; kk++) {
            const float4 a4 = *(const float4*)&As[kk][ty*4];
            const float4 b4 = *(const float4*)&Bs[kk][tx*4];
            const float av[4] = {a4.x, a4.y, a4.z, a4.w};
            const float bv[4] = {b4.x, b4.y, b4.z, b4.w};
            #pragma unroll
            for (int i = 0; i < 4; i++)
                #pragma unroll
                for (int j = 0; j < 4; j++)
                    acc[i][j] = fmaf(av[i], bv[j], acc[i][j]);
        }
        __syncthreads();
    }
    if (MODE == 0) {
        #pragma unroll
        for (int i = 0; i < 4; i++) {
            const int m = m0 + ty*4 + i;
            float4 o;
            o.x = acc[i][0] + bias[n0+tx*4+0];
            o.y = acc[i][1] + bias[n0+tx*4+1];
            o.z = acc[i][2] + bias[n0+tx*4+2];
            o.w = acc[i][3] + bias[n0+tx*4+3];
            *(float4*)&Y[m * N + n0 + tx*4] = o;
        }
    } else {
        #pragma unroll
        for (int i = 0; i < 4; i++) {
            const int m = m0 + ty*4 + i;
            const int b = m >> 11, s = m & (S_ - 1);
            #pragma unroll
            for (int j = 0; j < 4; j++) {
                const int n = n0 + tx*4 + j;
                const int h = n >> 6, d = n & 63;
                Y[((b * H_ + h) * S_ + s) * D_ + d] = acc[i][j] + bias[n];
            }
        }
    }
}

// ---------------- sumV[bh][d] = sum_j V[bh][j][d] ----------------
__global__ __launch_bounds__(256) void sumv_k(const float* __restrict__ V,
                                              float* __restrict__ sumV)
{
    const int bh = blockIdx.x;
    const int d = threadIdx.x & 63;
    const int g = threadIdx.x >> 6;
    float acc = 0.f;
    for (int j = g; j < S_; j += 4)
        acc += V[(bh * S_ + j) * D_ + d];
    __shared__ float part[4][D_];
    part[g][d] = acc;
    __syncthreads();
    if (threadIdx.x < 64)
        sumV[bh * D_ + d] = part[0][d] + part[1][d] + part[2][d] + part[3][d];
}

// ---------------- fused scores + exact top-204 + sparse-softmax AV ----------------
// 256 threads = 4 waves; cooperative scores, then each wave owns 2 rows
// barrier-free. XCD swizzle: blockIdx%8 = XCD (round-robin dispatch), so we
// map each XCD to exactly 4 bh values -> K+V working set 4 MB = one L2.
__global__ __launch_bounds__(256) void attn_topk_k(
    const float* __restrict__ Q, const float* __restrict__ Kg,
    const float* __restrict__ V, const float* __restrict__ sumV,
    float* __restrict__ AO)
{
    const int tid = threadIdx.x;
    const int wv = tid >> 6;
    const int lane = tid & 63;
    // XCD-locality remap (performance-only; any mapping is correct)
    const int xcd = blockIdx.x & 7;
    const int w = blockIdx.x >> 3;             // 0..1023
    const int bh = xcd * 4 + (w >> 8);         // 4 bh per XCD
    const int q0 = (w & 255) * QT_;
    const int b = bh >> 4, h = bh & (H_ - 1);

    __shared__ __align__(16) float sc[QT_][S_];      // 64 KB
    __shared__ __align__(16) float qs[QT_][D_];
    __shared__ __align__(16) unsigned hist[4][256];  // wave-private
    __shared__ __align__(16) int   list_j[4][224];   // wave-private
    __shared__ __align__(16) float list_w[4][224];

    for (int i = tid; i < QT_ * D_; i += 256)
        qs[i >> 6][i & 63] = Q[(bh * S_ + q0 + (i >> 6)) * D_ + (i & 63)];
    __syncthreads();

    // ---- cooperative scores: thread covers 4 q rows x 16 j's ----
    {
        const int qh = tid >> 7;
        const int jl = tid & 127;
        float acc[4][16];
        #pragma unroll
        for (int qq = 0; qq < 4; qq++)
            #pragma unroll
            for (int i = 0; i < 16; i++) acc[qq][i] = 0.f;
        #pragma unroll
        for (int db = 0; db < 4; db++) {
            float4 qv[4][4];
            #pragma unroll
            for (int qq = 0; qq < 4; qq++)
                #pragma unroll
                for (int dd = 0; dd < 4; dd++)
                    qv[qq][dd] = *(const float4*)&qs[qh*4+qq][db*16 + dd*4];
            for (int i = 0; i < 16; i++) {
                const float4* kp = (const float4*)&Kg[(bh * S_ + jl + 128*i) * D_];
                float4 kv[4];
                #pragma unroll
                for (int dd = 0; dd < 4; dd++) kv[dd] = kp[db*4 + dd];
                #pragma unroll
                for (int qq = 0; qq < 4; qq++) {
                    float s = 0.f;
                    #pragma unroll
                    for (int dd = 0; dd < 4; dd++) {
                        s = fmaf(kv[dd].x, qv[qq][dd].x, s);
                        s = fmaf(kv[dd].y, qv[qq][dd].y, s);
                        s = fmaf(kv[dd].z, qv[qq][dd].z, s);
                        s = fmaf(kv[dd].w, qv[qq][dd].w, s);
                    }
                    acc[qq][i] += s;
                }
            }
        }
        #pragma unroll
        for (int qq = 0; qq < 4; qq++)
            for (int i = 0; i < 16; i++)
                sc[qh*4+qq][jl + 128*i] = acc[qq][i] * 0.125f;
    }
    __syncthreads();

    const float* Vb = V + (size_t)bh * S_ * D_;

    for (int rr = 0; rr < 2; rr++) {
        const int qr = wv * 2 + rr;

        // row into registers: lane owns j = i*256 + lane*4 + k
        float4 v4[8];
        #pragma unroll
        for (int i = 0; i < 8; i++)
            v4[i] = *(const float4*)&sc[qr][i * 256 + lane * 4];

        float lm = -INFINITY;
        #pragma unroll
        for (int i = 0; i < 8; i++)
            lm = fmaxf(lm, fmaxf(fmaxf(v4[i].x, v4[i].y), fmaxf(v4[i].z, v4[i].w)));
        const float m = fmaxf(wave_max(lm), 0.0f);   // sparse row includes zeros

        // ---- exact radix select (wave-private, barrier-free) ----
        unsigned prefix = 0;
        int rem = KEEP_;
        #pragma unroll
        for (int pass = 3; pass >= 0; pass--) {
            const int shift = pass * 8;
            *(uint4*)&hist[wv][lane * 4] = make_uint4(0u, 0u, 0u, 0u);
            #pragma unroll
            for (int i = 0; i < 8; i++) {
                const float vv[4] = {v4[i].x, v4[i].y, v4[i].z, v4[i].w};
                #pragma unroll
                for (int k = 0; k < 4; k++) {
                    const unsigned u = f2u_ord(vv[k]);
                    const bool match = (pass == 3) ||
                        ((u >> (shift + 8)) == (prefix >> (shift + 8)));
                    if (match) atomicAdd(&hist[wv][(u >> shift) & 255u], 1u);
                }
            }
            const uint4 h4 = *(const uint4*)&hist[wv][lane * 4];
            const unsigned s3 = h4.w;
            const unsigned s2 = h4.z + s3;
            const unsigned s1 = h4.y + s2;
            const unsigned s0 = h4.x + s1;
            unsigned incl = s0;                       // suffix scan across lanes
            #pragma unroll
            for (int off = 1; off < 64; off <<= 1) {
                const unsigned t = __shfl_down(incl, off);
                if (lane + off < 64) incl += t;
            }
            const unsigned excl = incl - s0;
            const unsigned cge[4] = {excl + s0, excl + s1, excl + s2, excl + s3};
            const unsigned cgt[4] = {excl + s1, excl + s2, excl + s3, excl};
            unsigned pk = 0;
            bool found = false;
            #pragma unroll
            for (int k = 0; k < 4; k++) {
                if (cge[k] >= (unsigned)rem && cgt[k] < (unsigned)rem) {
                    found = true;
                    pk = ((unsigned)(lane * 4 + k) << 16) | cgt[k];
                }
            }
            const unsigned long long fm = __ballot(found);
            const int src = __builtin_ctzll(fm);
            pk = __shfl(pk, src);
            prefix |= (pk >> 16) << shift;
            rem -= (int)(pk & 0xffffu);
        }
        const unsigned T = prefix;
        const float expT = __expf(u2f_ord(T) - m);

        // ---- build list via ballot compaction (no atomics) ----
        float esum = 0.f;
        int base = 0;
        int eqTotal = 0;
        #pragma unroll
        for (int i = 0; i < 8; i++) {
            const float vv[4] = {v4[i].x, v4[i].y, v4[i].z, v4[i].w};
            #pragma unroll
            for (int k = 0; k < 4; k++) {
                const unsigned u = f2u_ord(vv[k]);
                const bool gt = u > T;
                const unsigned long long mg = __ballot(gt);
                if (gt) {
                    const int pos = base + (int)__popcll(mg & ((1ULL << lane) - 1ULL));
                    const float w = __expf(vv[k] - m);
                    list_j[wv][pos] = i * 256 + lane * 4 + k;
                    list_w[wv][pos] = w;
                    esum += w;
                }
                base += (int)__popcll(mg);
                eqTotal += (int)__popcll(__ballot(u == T));
            }
        }
        if (eqTotal == rem) {            // normal: take all ties
            #pragma unroll
            for (int i = 0; i < 8; i++) {
                const float vv[4] = {v4[i].x, v4[i].y, v4[i].z, v4[i].w};
                #pragma unroll
                for (int k = 0; k < 4; k++) {
                    const unsigned u = f2u_ord(vv[k]);
                    const bool eq = (u == T);
                    const unsigned long long mg = __ballot(eq);
                    if (eq) {
                        const int pos = base + (int)__popcll(mg & ((1ULL << lane) - 1ULL));
                        list_j[wv][pos] = i * 256 + lane * 4 + k;
                        list_w[wv][pos] = expT;
                    }
                    base += (int)__popcll(mg);
                }
            }
        } else if (lane == 0) {          // rare tie overflow: lowest-index order
            int p = base, need = rem;
            for (int j = 0; j < S_ && need > 0; j++) {
                if (f2u_ord(sc[qr][j]) == T) {
                    list_j[wv][p] = j; list_w[wv][p] = expT; p++; need--;
                }
            }
        }
        const float E = wave_sum(esum) + (float)rem * expT;

        __asm__ volatile("s_waitcnt lgkmcnt(0)" ::: "memory");

        // ---- AV gather: lane = d, 8 loads in flight per batch ----
        float accW = 0.f, accS = 0.f;
        #pragma unroll 1
        for (int p = 0; p < 200; p += 8) {
            const int4   ja = *(const int4*)&list_j[wv][p];
            const int4   jb = *(const int4*)&list_j[wv][p + 4];
            const float4 wa = *(const float4*)&list_w[wv][p];
            const float4 wb = *(const float4*)&list_w[wv][p + 4];
            const float a0 = Vb[ja.x * 64 + lane];
            const float a1 = Vb[ja.y * 64 + lane];
            const float a2 = Vb[ja.z * 64 + lane];
            const float a3 = Vb[ja.w * 64 + lane];
            const float a4 = Vb[jb.x * 64 + lane];
            const float a5 = Vb[jb.y * 64 + lane];
            const float a6 = Vb[jb.z * 64 + lane];
            const float a7 = Vb[jb.w * 64 + lane];
            accW = fmaf(wa.x, a0, accW);
            accW = fmaf(wa.y, a1, accW);
            accW = fmaf(wa.z, a2, accW);
            accW = fmaf(wa.w, a3, accW);
            accW = fmaf(wb.x, a4, accW);
            accW = fmaf(wb.y, a5, accW);
            accW = fmaf(wb.z, a6, accW);
            accW = fmaf(wb.w, a7, accW);
            accS += a0 + a1 + a2 + a3 + a4 + a5 + a6 + a7;
        }
        {   // tail: 200..203
            const int4   ja = *(const int4*)&list_j[wv][200];
            const float4 wa = *(const float4*)&list_w[wv][200];
            const float a0 = Vb[ja.x * 64 + lane];
            const float a1 = Vb[ja.y * 64 + lane];
            const float a2 = Vb[ja.z * 64 + lane];
            const float a3 = Vb[ja.w * 64 + lane];
            accW = fmaf(wa.x, a0, accW);
            accW = fmaf(wa.y, a1, accW);
            accW = fmaf(wa.z, a2, accW);
            accW = fmaf(wa.w, a3, accW);
            accS += a0 + a1 + a2 + a3;
        }
        const float em = __expf(-m);
        const float denom = E + (float)(S_ - KEEP_) * em;
        const float numer = accW + em * (sumV[bh * D_ + lane] - accS);
        AO[(b * S_ + q0 + qr) * HID_ + h * D_ + lane] = numer / denom;
    }
}

extern "C" void kernel_launch(void* const* d_in, const int* in_sizes, int n_in,
                              void* d_out, int out_size, void* d_ws, size_t ws_size,
                              hipStream_t stream) {
    const float* x  = (const float*)d_in[0];
    const float* Wq = (const float*)d_in[1];
    const float* bq = (const float*)d_in[2];
    const float* Wk = (const float*)d_in[3];
    const float* bk = (const float*)d_in[4];
    const float* Wv = (const float*)d_in[5];
    const float* bv = (const float*)d_in[6];
    const float* Wo = (const float*)d_in[7];
    const float* bo = (const float*)d_in[8];
    float* out = (float*)d_out;

    float* ws = (float*)d_ws;
    const size_t NQ = (size_t)B_ * H_ * S_ * D_;
    float* Qw = ws;
    float* Kw = ws + NQ;
    float* Vw = ws + 2 * NQ;
    float* AO = ws + 3 * NQ;
    float* sV = ws + 4 * NQ;

    dim3 blk(256);
    dim3 gg(HID_ / 64, (B_ * S_) / 64);
    gemm_f32_k<1><<<gg, blk, 0, stream>>>(x, Wq, bq, Qw, B_ * S_, HID_, HID_);
    gemm_f32_k<1><<<gg, blk, 0, stream>>>(x, Wk, bk, Kw, B_ * S_, HID_, HID_);
    gemm_f32_k<1><<<gg, blk, 0, stream>>>(x, Wv, bv, Vw, B_ * S_, HID_, HID_);
    sumv_k<<<dim3(B_ * H_), blk, 0, stream>>>(Vw, sV);
    attn_topk_k<<<dim3(B_ * H_ * (S_ / QT_)), blk, 0, stream>>>(Qw, Kw, Vw, sV, AO);
    gemm_f32_k<0><<<gg, blk, 0, stream>>>(AO, Wo, bo, out, B_ * S_, HID_, HID_);
}

// Round 5
// 1580.021 us; speedup vs baseline: 2.1177x; 1.8358x over previous
//
#include <hip/hip_runtime.h>
#include <math.h>

#define B_    2
#define S_    2048
#define HID_  1024
#define H_    16
#define D_    64
#define KEEP_ 204
#define QT_   8

typedef __attribute__((ext_vector_type(8))) short short8;
typedef __attribute__((ext_vector_type(4))) float f32x4;

// order-preserving fp32 -> uint32 mapping (larger float <=> larger uint)
__device__ __forceinline__ unsigned f2u_ord(float x) {
    unsigned b = __float_as_uint(x);
    return (b & 0x80000000u) ? ~b : (b | 0x80000000u);
}
__device__ __forceinline__ float u2f_ord(unsigned u) {
    unsigned b = (u & 0x80000000u) ? (u ^ 0x80000000u) : ~u;
    return __uint_as_float(b);
}
__device__ __forceinline__ float wave_sum(float x) {
    #pragma unroll
    for (int off = 32; off > 0; off >>= 1) x += __shfl_xor(x, off);
    return x;
}
__device__ __forceinline__ unsigned wave_max_u(unsigned x) {
    #pragma unroll
    for (int off = 32; off > 0; off >>= 1) {
        unsigned t = __shfl_xor(x, off);
        x = (t > x) ? t : x;
    }
    return x;
}
__device__ __forceinline__ unsigned short bf16rn(float x) {
    unsigned u = __float_as_uint(x);
    return (unsigned short)((u + 0x7fffu + ((u >> 16) & 1u)) >> 16);
}

// ---------------- GEMM: Y = A @ W + bias ----------------
// MODE 0: fp32 Y[m*N+n]
// MODE 1: fp32 heads layout [bh][s][d]
// MODE 2: bf16 hi/lo split, heads layout, value scaled by `scale` first
template <int MODE>
__global__ __launch_bounds__(256) void gemm_f32_k(
    const float* __restrict__ A, const float* __restrict__ W,
    const float* __restrict__ bias, float* __restrict__ Y,
    unsigned short* __restrict__ Yh, unsigned short* __restrict__ Yl,
    float scale, int M, int N, int Kd)
{
    __shared__ __align__(16) float As[16][64];
    __shared__ __align__(16) float Bs[16][64];
    const int tid = threadIdx.x;
    const int tx = tid & 15, ty = tid >> 4;
    const int n0 = blockIdx.x * 64, m0 = blockIdx.y * 64;
    float acc[4][4] = {};
    for (int k0 = 0; k0 < Kd; k0 += 16) {
        {
            const int c4 = tid & 3, r = tid >> 2;
            const float4 a4 = *(const float4*)&A[(m0 + r) * Kd + k0 + c4 * 4];
            As[c4*4+0][r] = a4.x; As[c4*4+1][r] = a4.y;
            As[c4*4+2][r] = a4.z; As[c4*4+3][r] = a4.w;
        }
        {
            const int r4 = tid & 15, c = tid >> 4;
            *(float4*)&Bs[c][r4*4] = *(const float4*)&W[(k0 + c) * N + n0 + r4*4];
        }
        __syncthreads();
        #pragma unroll
        for (int kk = 0; kk < 16; kk++) {
            const float4 a4 = *(const float4*)&As[kk][ty*4];
            const float4 b4 = *(const float4*)&Bs[kk][tx*4];
            const float av[4] = {a4.x, a4.y, a4.z, a4.w};
            const float bv[4] = {b4.x, b4.y, b4.z, b4.w};
            #pragma unroll
            for (int i = 0; i < 4; i++)
                #pragma unroll
                for (int j = 0; j < 4; j++)
                    acc[i][j] = fmaf(av[i], bv[j], acc[i][j]);
        }
        __syncthreads();
    }
    if (MODE == 0) {
        #pragma unroll
        for (int i = 0; i < 4; i++) {
            const int m = m0 + ty*4 + i;
            float4 o;
            o.x = acc[i][0] + bias[n0+tx*4+0];
            o.y = acc[i][1] + bias[n0+tx*4+1];
            o.z = acc[i][2] + bias[n0+tx*4+2];
            o.w = acc[i][3] + bias[n0+tx*4+3];
            *(float4*)&Y[m * N + n0 + tx*4] = o;
        }
    } else if (MODE == 1) {
        #pragma unroll
        for (int i = 0; i < 4; i++) {
            const int m = m0 + ty*4 + i;
            const int b = m >> 11, s = m & (S_ - 1);
            #pragma unroll
            for (int j = 0; j < 4; j++) {
                const int n = n0 + tx*4 + j;
                const int h = n >> 6, d = n & 63;
                Y[((b * H_ + h) * S_ + s) * D_ + d] = acc[i][j] + bias[n];
            }
        }
    } else {
        #pragma unroll
        for (int i = 0; i < 4; i++) {
            const int m = m0 + ty*4 + i;
            const int b = m >> 11, s = m & (S_ - 1);
            const int nb = n0 + tx*4;
            const int h = nb >> 6, d = nb & 63;
            unsigned short hv[4], lv[4];
            #pragma unroll
            for (int j = 0; j < 4; j++) {
                const float val = (acc[i][j] + bias[nb + j]) * scale;
                const unsigned short hb = bf16rn(val);
                hv[j] = hb;
                lv[j] = bf16rn(val - __uint_as_float((unsigned)hb << 16));
            }
            const size_t idx = ((size_t)(b * H_ + h) * S_ + s) * D_ + d;
            *(ushort4*)&Yh[idx] = make_ushort4(hv[0], hv[1], hv[2], hv[3]);
            *(ushort4*)&Yl[idx] = make_ushort4(lv[0], lv[1], lv[2], lv[3]);
        }
    }
}

// ---------------- sumV[bh][d] = sum_j V[bh][j][d] ----------------
__global__ __launch_bounds__(256) void sumv_k(const float* __restrict__ V,
                                              float* __restrict__ sumV)
{
    const int bh = blockIdx.x;
    const int d = threadIdx.x & 63;
    const int g = threadIdx.x >> 6;
    float acc = 0.f;
    for (int j = g; j < S_; j += 4)
        acc += V[(bh * S_ + j) * D_ + d];
    __shared__ float part[4][D_];
    part[g][d] = acc;
    __syncthreads();
    if (threadIdx.x < 64)
        sumV[bh * D_ + d] = part[0][d] + part[1][d] + part[2][d] + part[3][d];
}

// ---------------- fused MFMA scores + exact top-204 + sparse-softmax AV ----------------
// 4 waves/block. Scores via split-bf16 MFMA (hihi+hilo+lohi+lolo ~ fp32-exact).
// Chunked wave->wave redistribution through a 32 KB LDS buffer (2 rounds),
// each wave then holds its 2 rows in registers (ordered-uint form).
// hist/lists overlay the dead score buffer. ~33 KB LDS -> 4 blocks/CU.
__global__ __launch_bounds__(256, 4) void attn_topk_k(
    const unsigned short* __restrict__ Qhi, const unsigned short* __restrict__ Qlo,
    const unsigned short* __restrict__ Khi, const unsigned short* __restrict__ Klo,
    const float* __restrict__ V, const float* __restrict__ sumV,
    float* __restrict__ AO)
{
    const int tid = threadIdx.x;
    const int wv = tid >> 6;
    const int lane = tid & 63;
    // XCD-locality remap: 4 bh per XCD -> K+V working set ~4 MB ~ one L2
    const int xcd = blockIdx.x & 7;
    const int w = blockIdx.x >> 3;
    const int bh = xcd * 4 + (w >> 8);
    const int q0 = (w & 255) * QT_;
    const int b = bh >> 4, h = bh & (H_ - 1);

    __shared__ __align__(16) float sc[QT_][1024];    // 32 KB, overlaid in select phase
    unsigned* hist_base = (unsigned*)&sc[0][0];      // [4][256]  (4 KB)
    int*      lj_base   = (int*)&sc[1][0];           // [4][224]  (3.5 KB)
    float*    lw_base   = (float*)&sc[2][0];         // [4][224]

    const int mrow = lane & 15, quad = lane >> 4;

    // ---- A-fragments: Q hi/lo, rows duplicated (m&7) so no masking needed ----
    const size_t qrow = ((size_t)bh * S_ + q0 + (mrow & 7)) * D_;
    const short8 Ah0 = *(const short8*)&Qhi[qrow + quad * 8];
    const short8 Ah1 = *(const short8*)&Qhi[qrow + 32 + quad * 8];
    const short8 Al0 = *(const short8*)&Qlo[qrow + quad * 8];
    const short8 Al1 = *(const short8*)&Qlo[qrow + 32 + quad * 8];

    unsigned uu[2][32];   // my 2 rows, ordered-uint scores; element c <-> j = c*64+lane
    const size_t kbase = (size_t)bh * S_ * D_;

    #pragma unroll
    for (int r = 0; r < 2; r++) {
        // ---- 16 MFMA tiles (j = wv*512 + r*256 + tl*16 + col), pipelined B loads ----
        int jrow = wv * 512 + r * 256 + mrow;
        size_t koff = kbase + (size_t)jrow * D_ + quad * 8;
        short8 Bh0 = *(const short8*)&Khi[koff];
        short8 Bh1 = *(const short8*)&Khi[koff + 32];
        short8 Bl0 = *(const short8*)&Klo[koff];
        short8 Bl1 = *(const short8*)&Klo[koff + 32];
        #pragma unroll 1
        for (int tl = 0; tl < 16; tl++) {
            short8 Ch0, Ch1, Cl0, Cl1;
            if (tl < 15) {
                const size_t kn = koff + (size_t)16 * D_ * (tl + 1) - (size_t)16 * D_ * tl;
                const size_t k2 = koff + (size_t)16 * D_;
                Ch0 = *(const short8*)&Khi[k2];
                Ch1 = *(const short8*)&Khi[k2 + 32];
                Cl0 = *(const short8*)&Klo[k2];
                Cl1 = *(const short8*)&Klo[k2 + 32];
                (void)kn;
            }
            f32x4 acc0 = {0.f, 0.f, 0.f, 0.f};
            f32x4 acc1 = {0.f, 0.f, 0.f, 0.f};
            acc0 = __builtin_amdgcn_mfma_f32_16x16x32_bf16(Al0, Bl0, acc0, 0, 0, 0);
            acc1 = __builtin_amdgcn_mfma_f32_16x16x32_bf16(Al1, Bl1, acc1, 0, 0, 0);
            acc0 = __builtin_amdgcn_mfma_f32_16x16x32_bf16(Al0, Bh0, acc0, 0, 0, 0);
            acc1 = __builtin_amdgcn_mfma_f32_16x16x32_bf16(Al1, Bh1, acc1, 0, 0, 0);
            acc0 = __builtin_amdgcn_mfma_f32_16x16x32_bf16(Ah0, Bl0, acc0, 0, 0, 0);
            acc1 = __builtin_amdgcn_mfma_f32_16x16x32_bf16(Ah1, Bl1, acc1, 0, 0, 0);
            acc0 = __builtin_amdgcn_mfma_f32_16x16x32_bf16(Ah0, Bh0, acc0, 0, 0, 0);
            acc1 = __builtin_amdgcn_mfma_f32_16x16x32_bf16(Ah1, Bh1, acc1, 0, 0, 0);
            if (lane < 32) {   // C rows 0..7 live in lanes 0..31 (quad*4+reg, col=lane&15)
                const int colb = wv * 256 + tl * 16 + (lane & 15);
                #pragma unroll
                for (int reg = 0; reg < 4; reg++)
                    sc[quad * 4 + reg][colb] = acc0[reg] + acc1[reg];
            }
            Bh0 = Ch0; Bh1 = Ch1; Bl0 = Cl0; Bl1 = Cl1;
            koff += (size_t)16 * D_;
        }
        __syncthreads();   // all waves' round-r tiles written
        // ---- read my 2 rows' round-r elements (stride-1, conflict-free) ----
        #pragma unroll
        for (int cc = 0; cc < 16; cc++) {
            const int c = (cc & 3) | (r << 2) | ((cc >> 2) << 3);
            const int addr = (c >> 3) * 256 + (c & 3) * 64 + lane;
            uu[0][c] = f2u_ord(sc[2 * wv + 0][addr]);
            uu[1][c] = f2u_ord(sc[2 * wv + 1][addr]);
        }
        __syncthreads();   // reads done before next round overwrites / overlay reuse
    }

    unsigned* histw = hist_base + wv * 256;
    int*      lj    = lj_base + wv * 224;
    float*    lw    = lw_base + wv * 224;
    const float* Vb = V + (size_t)bh * S_ * D_;

    #pragma unroll 1
    for (int rr = 0; rr < 2; rr++) {
        const int qr = wv * 2 + rr;

        // row max (ordered uints); sparse row includes zeros -> clamp to 0
        unsigned um = 0u;
        #pragma unroll
        for (int c = 0; c < 32; c++) { const unsigned t = uu[rr][c]; um = (t > um) ? t : um; }
        um = wave_max_u(um);
        const float m = fmaxf(u2f_ord(um), 0.0f);

        // ---- exact radix select (wave-private, barrier-free) ----
        unsigned prefix = 0;
        int rem = KEEP_;
        #pragma unroll
        for (int pass = 3; pass >= 0; pass--) {
            const int shift = pass * 8;
            *(uint4*)&histw[lane * 4] = make_uint4(0u, 0u, 0u, 0u);
            #pragma unroll
            for (int c = 0; c < 32; c++) {
                const unsigned u = uu[rr][c];
                const bool match = (pass == 3) ||
                    ((u >> (shift + 8)) == (prefix >> (shift + 8)));
                if (match) atomicAdd(&histw[(u >> shift) & 255u], 1u);
            }
            const uint4 h4 = *(const uint4*)&histw[lane * 4];
            const unsigned s3 = h4.w;
            const unsigned s2 = h4.z + s3;
            const unsigned s1 = h4.y + s2;
            const unsigned s0 = h4.x + s1;
            unsigned incl = s0;                       // suffix scan across lanes
            #pragma unroll
            for (int off = 1; off < 64; off <<= 1) {
                const unsigned t = __shfl_down(incl, off);
                if (lane + off < 64) incl += t;
            }
            const unsigned excl = incl - s0;
            const unsigned cge[4] = {excl + s0, excl + s1, excl + s2, excl + s3};
            const unsigned cgt[4] = {excl + s1, excl + s2, excl + s3, excl};
            unsigned pk = 0;
            bool found = false;
            #pragma unroll
            for (int k = 0; k < 4; k++) {
                if (cge[k] >= (unsigned)rem && cgt[k] < (unsigned)rem) {
                    found = true;
                    pk = ((unsigned)(lane * 4 + k) << 16) | cgt[k];
                }
            }
            const unsigned long long fm = __ballot(found);
            const int src = __builtin_ctzll(fm);
            pk = __shfl(pk, src);
            prefix |= (pk >> 16) << shift;
            rem -= (int)(pk & 0xffffu);
        }
        const unsigned T = prefix;
        const float expT = __expf(u2f_ord(T) - m);
        const unsigned long long below = (1ULL << lane) - 1ULL;

        // ---- list build: all > T via ballot compaction ----
        float esum = 0.f;
        int base = 0;
        #pragma unroll
        for (int c = 0; c < 32; c++) {
            const unsigned u = uu[rr][c];
            const bool gt = u > T;
            const unsigned long long mg = __ballot(gt);
            if (gt) {
                const int pos = base + (int)__popcll(mg & below);
                const float wgt = __expf(u2f_ord(u) - m);
                lj[pos] = c * 64 + lane;
                lw[pos] = wgt;
                esum += wgt;
            }
            base += (int)__popcll(mg);
        }
        // ---- ties: first `rem` in ascending j (jax stable tie-break) ----
        int need = rem;
        #pragma unroll
        for (int c = 0; c < 32; c++) {
            const unsigned u = uu[rr][c];
            const bool eq = (u == T);
            const unsigned long long mg = __ballot(eq);
            if (eq) {
                const int pic = (int)__popcll(mg & below);
                if (pic < need) { lj[base + pic] = c * 64 + lane; lw[base + pic] = expT; }
            }
            const int cnt = (int)__popcll(mg);
            const int take = (cnt < need) ? cnt : need;
            base += take;
            need -= take;
        }
        const float E = wave_sum(esum) + (float)rem * expT;

        __asm__ volatile("s_waitcnt lgkmcnt(0)" ::: "memory");

        // ---- AV gather: lane = d, 8 loads in flight per batch ----
        float accW = 0.f, accS = 0.f;
        #pragma unroll 1
        for (int p = 0; p < 200; p += 8) {
            const int4   ja = *(const int4*)&lj[p];
            const int4   jb = *(const int4*)&lj[p + 4];
            const float4 wa = *(const float4*)&lw[p];
            const float4 wb = *(const float4*)&lw[p + 4];
            const float a0 = Vb[ja.x * 64 + lane];
            const float a1 = Vb[ja.y * 64 + lane];
            const float a2 = Vb[ja.z * 64 + lane];
            const float a3 = Vb[ja.w * 64 + lane];
            const float a4 = Vb[jb.x * 64 + lane];
            const float a5 = Vb[jb.y * 64 + lane];
            const float a6 = Vb[jb.z * 64 + lane];
            const float a7 = Vb[jb.w * 64 + lane];
            accW = fmaf(wa.x, a0, accW);
            accW = fmaf(wa.y, a1, accW);
            accW = fmaf(wa.z, a2, accW);
            accW = fmaf(wa.w, a3, accW);
            accW = fmaf(wb.x, a4, accW);
            accW = fmaf(wb.y, a5, accW);
            accW = fmaf(wb.z, a6, accW);
            accW = fmaf(wb.w, a7, accW);
            accS += a0 + a1 + a2 + a3 + a4 + a5 + a6 + a7;
        }
        {   // tail 200..203
            const int4   ja = *(const int4*)&lj[200];
            const float4 wa = *(const float4*)&lw[200];
            const float a0 = Vb[ja.x * 64 + lane];
            const float a1 = Vb[ja.y * 64 + lane];
            const float a2 = Vb[ja.z * 64 + lane];
            const float a3 = Vb[ja.w * 64 + lane];
            accW = fmaf(wa.x, a0, accW);
            accW = fmaf(wa.y, a1, accW);
            accW = fmaf(wa.z, a2, accW);
            accW = fmaf(wa.w, a3, accW);
            accS += a0 + a1 + a2 + a3;
        }
        const float em = __expf(-m);
        const float denom = E + (float)(S_ - KEEP_) * em;
        const float numer = accW + em * (sumV[bh * D_ + lane] - accS);
        AO[(b * S_ + q0 + qr) * HID_ + h * D_ + lane] = numer / denom;
    }
}

extern "C" void kernel_launch(void* const* d_in, const int* in_sizes, int n_in,
                              void* d_out, int out_size, void* d_ws, size_t ws_size,
                              hipStream_t stream) {
    const float* x  = (const float*)d_in[0];
    const float* Wq = (const float*)d_in[1];
    const float* bq = (const float*)d_in[2];
    const float* Wk = (const float*)d_in[3];
    const float* bk = (const float*)d_in[4];
    const float* Wv = (const float*)d_in[5];
    const float* bv = (const float*)d_in[6];
    const float* Wo = (const float*)d_in[7];
    const float* bo = (const float*)d_in[8];
    float* out = (float*)d_out;

    const size_t NQ = (size_t)B_ * H_ * S_ * D_;   // 4,194,304
    unsigned short* Qhi = (unsigned short*)d_ws;
    unsigned short* Qlo = Qhi + NQ;
    unsigned short* Khi = Qlo + NQ;
    unsigned short* Klo = Khi + NQ;
    float* Vw = (float*)(Klo + NQ);
    float* AO = Vw + NQ;
    float* sV = AO + NQ;

    dim3 blk(256);
    dim3 gg(HID_ / 64, (B_ * S_) / 64);
    gemm_f32_k<2><<<gg, blk, 0, stream>>>(x, Wq, bq, nullptr, Qhi, Qlo, 0.125f, B_ * S_, HID_, HID_);
    gemm_f32_k<2><<<gg, blk, 0, stream>>>(x, Wk, bk, nullptr, Khi, Klo, 1.0f,   B_ * S_, HID_, HID_);
    gemm_f32_k<1><<<gg, blk, 0, stream>>>(x, Wv, bv, Vw, nullptr, nullptr, 1.0f, B_ * S_, HID_, HID_);
    sumv_k<<<dim3(B_ * H_), blk, 0, stream>>>(Vw, sV);
    attn_topk_k<<<dim3(B_ * H_ * (S_ / QT_)), blk, 0, stream>>>(Qhi, Qlo, Khi, Klo, Vw, sV, AO);
    gemm_f32_k<0><<<gg, blk, 0, stream>>>(AO, Wo, bo, out, nullptr, nullptr, 1.0f, B_ * S_, HID_, HID_);
}

// Round 6
// 1479.085 us; speedup vs baseline: 2.2622x; 1.0682x over previous
//
#include <hip/hip_runtime.h>
#include <math.h>

#define B_    2
#define S_    2048
#define HID_  1024
#define H_    16
#define D_    64
#define KEEP_ 204
#define QT_   8

typedef __attribute__((ext_vector_type(8))) short short8;
typedef __attribute__((ext_vector_type(4))) float f32x4;

// order-preserving fp32 -> uint32 mapping (larger float <=> larger uint)
__device__ __forceinline__ unsigned f2u_ord(float x) {
    unsigned b = __float_as_uint(x);
    return (b & 0x80000000u) ? ~b : (b | 0x80000000u);
}
__device__ __forceinline__ float u2f_ord(unsigned u) {
    unsigned b = (u & 0x80000000u) ? (u ^ 0x80000000u) : ~u;
    return __uint_as_float(b);
}
__device__ __forceinline__ float wave_sum(float x) {
    #pragma unroll
    for (int off = 32; off > 0; off >>= 1) x += __shfl_xor(x, off);
    return x;
}
__device__ __forceinline__ unsigned wave_max_u(unsigned x) {
    #pragma unroll
    for (int off = 32; off > 0; off >>= 1) {
        unsigned t = __shfl_xor(x, off);
        x = (t > x) ? t : x;
    }
    return x;
}
__device__ __forceinline__ unsigned short bf16rn(float x) {
    unsigned u = __float_as_uint(x);
    return (unsigned short)((u + 0x7fffu + ((u >> 16) & 1u)) >> 16);
}

// ---------------- GEMM: Y = A @ W + bias ----------------
// MODE 0: fp32 Y[m*N+n]
// MODE 1: fp32 heads layout [bh][s][d]
// MODE 2: bf16 hi/lo split, heads layout, value scaled by `scale` first
template <int MODE>
__global__ __launch_bounds__(256) void gemm_f32_k(
    const float* __restrict__ A, const float* __restrict__ W,
    const float* __restrict__ bias, float* __restrict__ Y,
    unsigned short* __restrict__ Yh, unsigned short* __restrict__ Yl,
    float scale, int M, int N, int Kd)
{
    __shared__ __align__(16) float As[16][64];
    __shared__ __align__(16) float Bs[16][64];
    const int tid = threadIdx.x;
    const int tx = tid & 15, ty = tid >> 4;
    const int n0 = blockIdx.x * 64, m0 = blockIdx.y * 64;
    float acc[4][4] = {};
    for (int k0 = 0; k0 < Kd; k0 += 16) {
        {
            const int c4 = tid & 3, r = tid >> 2;
            const float4 a4 = *(const float4*)&A[(m0 + r) * Kd + k0 + c4 * 4];
            As[c4*4+0][r] = a4.x; As[c4*4+1][r] = a4.y;
            As[c4*4+2][r] = a4.z; As[c4*4+3][r] = a4.w;
        }
        {
            const int r4 = tid & 15, c = tid >> 4;
            *(float4*)&Bs[c][r4*4] = *(const float4*)&W[(k0 + c) * N + n0 + r4*4];
        }
        __syncthreads();
        #pragma unroll
        for (int kk = 0; kk < 16; kk++) {
            const float4 a4 = *(const float4*)&As[kk][ty*4];
            const float4 b4 = *(const float4*)&Bs[kk][tx*4];
            const float av[4] = {a4.x, a4.y, a4.z, a4.w};
            const float bv[4] = {b4.x, b4.y, b4.z, b4.w};
            #pragma unroll
            for (int i = 0; i < 4; i++)
                #pragma unroll
                for (int j = 0; j < 4; j++)
                    acc[i][j] = fmaf(av[i], bv[j], acc[i][j]);
        }
        __syncthreads();
    }
    if (MODE == 0) {
        #pragma unroll
        for (int i = 0; i < 4; i++) {
            const int m = m0 + ty*4 + i;
            float4 o;
            o.x = acc[i][0] + bias[n0+tx*4+0];
            o.y = acc[i][1] + bias[n0+tx*4+1];
            o.z = acc[i][2] + bias[n0+tx*4+2];
            o.w = acc[i][3] + bias[n0+tx*4+3];
            *(float4*)&Y[m * N + n0 + tx*4] = o;
        }
    } else if (MODE == 1) {
        #pragma unroll
        for (int i = 0; i < 4; i++) {
            const int m = m0 + ty*4 + i;
            const int b = m >> 11, s = m & (S_ - 1);
            #pragma unroll
            for (int j = 0; j < 4; j++) {
                const int n = n0 + tx*4 + j;
                const int h = n >> 6, d = n & 63;
                Y[((b * H_ + h) * S_ + s) * D_ + d] = acc[i][j] + bias[n];
            }
        }
    } else {
        #pragma unroll
        for (int i = 0; i < 4; i++) {
            const int m = m0 + ty*4 + i;
            const int b = m >> 11, s = m & (S_ - 1);
            const int nb = n0 + tx*4;
            const int h = nb >> 6, d = nb & 63;
            unsigned short hv[4], lv[4];
            #pragma unroll
            for (int j = 0; j < 4; j++) {
                const float val = (acc[i][j] + bias[nb + j]) * scale;
                const unsigned short hb = bf16rn(val);
                hv[j] = hb;
                lv[j] = bf16rn(val - __uint_as_float((unsigned)hb << 16));
            }
            const size_t idx = ((size_t)(b * H_ + h) * S_ + s) * D_ + d;
            *(ushort4*)&Yh[idx] = make_ushort4(hv[0], hv[1], hv[2], hv[3]);
            *(ushort4*)&Yl[idx] = make_ushort4(lv[0], lv[1], lv[2], lv[3]);
        }
    }
}

// ---------------- sumV[bh][d] = sum_j V[bh][j][d] ----------------
__global__ __launch_bounds__(256) void sumv_k(const float* __restrict__ V,
                                              float* __restrict__ sumV)
{
    const int bh = blockIdx.x;
    const int d = threadIdx.x & 63;
    const int g = threadIdx.x >> 6;
    float acc = 0.f;
    for (int j = g; j < S_; j += 4)
        acc += V[(bh * S_ + j) * D_ + d];
    __shared__ float part[4][D_];
    part[g][d] = acc;
    __syncthreads();
    if (threadIdx.x < 64)
        sumV[bh * D_ + d] = part[0][d] + part[1][d] + part[2][d] + part[3][d];
}

// ---------------- fused MFMA scores + exact top-204 + sparse-softmax AV ----------------
// 512 threads = 8 waves; ONE query row per wave (no multi-row register arrays ->
// no dynamic-index spill; R5's uu[2][32] with runtime rr cost ~1 GB of scratch).
// Single score pass into sc[8][2048] (64 KB), then each wave extracts its row
// into uu[32] (statically indexed -> VGPRs) and runs barrier-free select+gather.
// hist/lists overlay dead sc. 3 barriers total.
__global__ __launch_bounds__(512, 4) void attn_topk_k(
    const unsigned short* __restrict__ Qhi, const unsigned short* __restrict__ Qlo,
    const unsigned short* __restrict__ Khi, const unsigned short* __restrict__ Klo,
    const float* __restrict__ V, const float* __restrict__ sumV,
    float* __restrict__ AO)
{
    const int tid = threadIdx.x;
    const int wv = tid >> 6;                  // 0..7 — this wave's query row
    const int lane = tid & 63;
    // XCD-locality remap: 4 bh per XCD -> K+V working set ~4 MB ~ one L2
    const int xcd = blockIdx.x & 7;
    const int w = blockIdx.x >> 3;
    const int bh = xcd * 4 + (w >> 8);
    const int q0 = (w & 255) * QT_;
    const int b = bh >> 4, h = bh & (H_ - 1);

    __shared__ __align__(16) float sc[QT_][S_];      // 64 KB; overlaid after extraction
    unsigned* hist_base = (unsigned*)&sc[0][0];      // 8 waves x 256 u32 = 8 KB (= sc row 0)
    int*      lj_base   = (int*)&sc[1][0];           // 8 x 224 int  (= sc row 1)
    float*    lw_base   = (float*)&sc[2][0];         // 8 x 224 f32  (= sc row 2)

    const int mrow = lane & 15, quad = lane >> 4;

    // ---- A-fragments: Q hi/lo, rows duplicated (m&7) so no masking needed ----
    const size_t qrow = ((size_t)bh * S_ + q0 + (mrow & 7)) * D_;
    const short8 Ah0 = *(const short8*)&Qhi[qrow + quad * 8];
    const short8 Ah1 = *(const short8*)&Qhi[qrow + 32 + quad * 8];
    const short8 Al0 = *(const short8*)&Qlo[qrow + quad * 8];
    const short8 Al1 = *(const short8*)&Qlo[qrow + 32 + quad * 8];

    const size_t kbase = (size_t)bh * S_ * D_;

    // ---- scores: wave covers columns [wv*256, wv*256+256), all 8 rows ----
    {
        size_t koff = kbase + (size_t)(wv * 256 + mrow) * D_ + quad * 8;
        short8 Bh0 = *(const short8*)&Khi[koff];
        short8 Bh1 = *(const short8*)&Khi[koff + 32];
        short8 Bl0 = *(const short8*)&Klo[koff];
        short8 Bl1 = *(const short8*)&Klo[koff + 32];
        #pragma unroll 1
        for (int tl = 0; tl < 16; tl++) {
            short8 Ch0, Ch1, Cl0, Cl1;
            if (tl < 15) {
                const size_t k2 = koff + (size_t)16 * D_;
                Ch0 = *(const short8*)&Khi[k2];
                Ch1 = *(const short8*)&Khi[k2 + 32];
                Cl0 = *(const short8*)&Klo[k2];
                Cl1 = *(const short8*)&Klo[k2 + 32];
            }
            f32x4 acc0 = {0.f, 0.f, 0.f, 0.f};
            f32x4 acc1 = {0.f, 0.f, 0.f, 0.f};
            acc0 = __builtin_amdgcn_mfma_f32_16x16x32_bf16(Al0, Bl0, acc0, 0, 0, 0);
            acc1 = __builtin_amdgcn_mfma_f32_16x16x32_bf16(Al1, Bl1, acc1, 0, 0, 0);
            acc0 = __builtin_amdgcn_mfma_f32_16x16x32_bf16(Al0, Bh0, acc0, 0, 0, 0);
            acc1 = __builtin_amdgcn_mfma_f32_16x16x32_bf16(Al1, Bh1, acc1, 0, 0, 0);
            acc0 = __builtin_amdgcn_mfma_f32_16x16x32_bf16(Ah0, Bl0, acc0, 0, 0, 0);
            acc1 = __builtin_amdgcn_mfma_f32_16x16x32_bf16(Ah1, Bl1, acc1, 0, 0, 0);
            acc0 = __builtin_amdgcn_mfma_f32_16x16x32_bf16(Ah0, Bh0, acc0, 0, 0, 0);
            acc1 = __builtin_amdgcn_mfma_f32_16x16x32_bf16(Ah1, Bh1, acc1, 0, 0, 0);
            if (lane < 32) {   // C rows 0..7 live in lanes 0..31 (row=quad*4+reg, col=lane&15)
                const int colb = wv * 256 + tl * 16 + (lane & 15);
                #pragma unroll
                for (int reg = 0; reg < 4; reg++)
                    sc[quad * 4 + reg][colb] = acc0[reg] + acc1[reg];
            }
            Bh0 = Ch0; Bh1 = Ch1; Bl0 = Cl0; Bl1 = Cl1;
            koff += (size_t)16 * D_;
        }
    }
    __syncthreads();   // all strips written

    // ---- extract MY row into registers (static indices -> VGPRs) ----
    unsigned uu[32];   // element c <-> j = c*64 + lane
    #pragma unroll
    for (int c = 0; c < 32; c++)
        uu[c] = f2u_ord(sc[wv][c * 64 + lane]);
    __syncthreads();   // sc dead; overlays (hist/lists) may now be written

    unsigned* histw = hist_base + wv * 256;
    int*      lj    = lj_base + wv * 224;
    float*    lw    = lw_base + wv * 224;
    const float* Vb = V + kbase;

    // row max (ordered uints); sparse row includes zeros -> clamp to 0
    unsigned um = 0u;
    #pragma unroll
    for (int c = 0; c < 32; c++) { const unsigned t = uu[c]; um = (t > um) ? t : um; }
    um = wave_max_u(um);
    const float m = fmaxf(u2f_ord(um), 0.0f);

    // ---- exact radix select (wave-private, barrier-free) ----
    unsigned prefix = 0;
    int rem = KEEP_;
    #pragma unroll
    for (int pass = 3; pass >= 0; pass--) {
        const int shift = pass * 8;
        *(uint4*)&histw[lane * 4] = make_uint4(0u, 0u, 0u, 0u);
        #pragma unroll
        for (int c = 0; c < 32; c++) {
            const unsigned u = uu[c];
            const bool match = (pass == 3) ||
                ((u >> (shift + 8)) == (prefix >> (shift + 8)));
            if (match) atomicAdd(&histw[(u >> shift) & 255u], 1u);
        }
        const uint4 h4 = *(const uint4*)&histw[lane * 4];
        const unsigned s3 = h4.w;
        const unsigned s2 = h4.z + s3;
        const unsigned s1 = h4.y + s2;
        const unsigned s0 = h4.x + s1;
        unsigned incl = s0;                       // suffix scan across lanes
        #pragma unroll
        for (int off = 1; off < 64; off <<= 1) {
            const unsigned t = __shfl_down(incl, off);
            if (lane + off < 64) incl += t;
        }
        const unsigned excl = incl - s0;
        const unsigned cge[4] = {excl + s0, excl + s1, excl + s2, excl + s3};
        const unsigned cgt[4] = {excl + s1, excl + s2, excl + s3, excl};
        unsigned pk = 0;
        bool found = false;
        #pragma unroll
        for (int k = 0; k < 4; k++) {
            if (cge[k] >= (unsigned)rem && cgt[k] < (unsigned)rem) {
                found = true;
                pk = ((unsigned)(lane * 4 + k) << 16) | cgt[k];
            }
        }
        const unsigned long long fm = __ballot(found);
        const int src = __builtin_ctzll(fm);
        pk = __shfl(pk, src);
        prefix |= (pk >> 16) << shift;
        rem -= (int)(pk & 0xffffu);
    }
    const unsigned T = prefix;
    const float expT = __expf(u2f_ord(T) - m);
    const unsigned long long below = (1ULL << lane) - 1ULL;

    // ---- list build: all > T via ballot compaction ----
    float esum = 0.f;
    int base = 0;
    #pragma unroll
    for (int c = 0; c < 32; c++) {
        const unsigned u = uu[c];
        const bool gt = u > T;
        const unsigned long long mg = __ballot(gt);
        if (gt) {
            const int pos = base + (int)__popcll(mg & below);
            const float wgt = __expf(u2f_ord(u) - m);
            lj[pos] = c * 64 + lane;
            lw[pos] = wgt;
            esum += wgt;
        }
        base += (int)__popcll(mg);
    }
    // ---- ties: first `rem` in ascending j (jax stable tie-break) ----
    int need = rem;
    #pragma unroll
    for (int c = 0; c < 32; c++) {
        const unsigned u = uu[c];
        const bool eq = (u == T);
        const unsigned long long mg = __ballot(eq);
        if (eq) {
            const int pic = (int)__popcll(mg & below);
            if (pic < need) { lj[base + pic] = c * 64 + lane; lw[base + pic] = expT; }
        }
        const int cnt = (int)__popcll(mg);
        const int take = (cnt < need) ? cnt : need;
        base += take;
        need -= take;
    }
    const float E = wave_sum(esum) + (float)rem * expT;

    __asm__ volatile("s_waitcnt lgkmcnt(0)" ::: "memory");

    // ---- AV gather: lane = d, 8 loads in flight per batch ----
    float accW = 0.f, accS = 0.f;
    #pragma unroll 1
    for (int p = 0; p < 200; p += 8) {
        const int4   ja = *(const int4*)&lj[p];
        const int4   jb = *(const int4*)&lj[p + 4];
        const float4 wa = *(const float4*)&lw[p];
        const float4 wb = *(const float4*)&lw[p + 4];
        const float a0 = Vb[ja.x * 64 + lane];
        const float a1 = Vb[ja.y * 64 + lane];
        const float a2 = Vb[ja.z * 64 + lane];
        const float a3 = Vb[ja.w * 64 + lane];
        const float a4 = Vb[jb.x * 64 + lane];
        const float a5 = Vb[jb.y * 64 + lane];
        const float a6 = Vb[jb.z * 64 + lane];
        const float a7 = Vb[jb.w * 64 + lane];
        accW = fmaf(wa.x, a0, accW);
        accW = fmaf(wa.y, a1, accW);
        accW = fmaf(wa.z, a2, accW);
        accW = fmaf(wa.w, a3, accW);
        accW = fmaf(wb.x, a4, accW);
        accW = fmaf(wb.y, a5, accW);
        accW = fmaf(wb.z, a6, accW);
        accW = fmaf(wb.w, a7, accW);
        accS += a0 + a1 + a2 + a3 + a4 + a5 + a6 + a7;
    }
    {   // tail 200..203
        const int4   ja = *(const int4*)&lj[200];
        const float4 wa = *(const float4*)&lw[200];
        const float a0 = Vb[ja.x * 64 + lane];
        const float a1 = Vb[ja.y * 64 + lane];
        const float a2 = Vb[ja.z * 64 + lane];
        const float a3 = Vb[ja.w * 64 + lane];
        accW = fmaf(wa.x, a0, accW);
        accW = fmaf(wa.y, a1, accW);
        accW = fmaf(wa.z, a2, accW);
        accW = fmaf(wa.w, a3, accW);
        accS += a0 + a1 + a2 + a3;
    }
    const float em = __expf(-m);
    const float denom = E + (float)(S_ - KEEP_) * em;
    const float numer = accW + em * (sumV[bh * D_ + lane] - accS);
    AO[(b * S_ + q0 + wv) * HID_ + h * D_ + lane] = numer / denom;
}

extern "C" void kernel_launch(void* const* d_in, const int* in_sizes, int n_in,
                              void* d_out, int out_size, void* d_ws, size_t ws_size,
                              hipStream_t stream) {
    const float* x  = (const float*)d_in[0];
    const float* Wq = (const float*)d_in[1];
    const float* bq = (const float*)d_in[2];
    const float* Wk = (const float*)d_in[3];
    const float* bk = (const float*)d_in[4];
    const float* Wv = (const float*)d_in[5];
    const float* bv = (const float*)d_in[6];
    const float* Wo = (const float*)d_in[7];
    const float* bo = (const float*)d_in[8];
    float* out = (float*)d_out;

    const size_t NQ = (size_t)B_ * H_ * S_ * D_;   // 4,194,304
    unsigned short* Qhi = (unsigned short*)d_ws;
    unsigned short* Qlo = Qhi + NQ;
    unsigned short* Khi = Qlo + NQ;
    unsigned short* Klo = Khi + NQ;
    float* Vw = (float*)(Klo + NQ);
    float* AO = Vw + NQ;
    float* sV = AO + NQ;

    dim3 blk(256);
    dim3 gg(HID_ / 64, (B_ * S_) / 64);
    gemm_f32_k<2><<<gg, blk, 0, stream>>>(x, Wq, bq, nullptr, Qhi, Qlo, 0.125f, B_ * S_, HID_, HID_);
    gemm_f32_k<2><<<gg, blk, 0, stream>>>(x, Wk, bk, nullptr, Khi, Klo, 1.0f,   B_ * S_, HID_, HID_);
    gemm_f32_k<1><<<gg, blk, 0, stream>>>(x, Wv, bv, Vw, nullptr, nullptr, 1.0f, B_ * S_, HID_, HID_);
    sumv_k<<<dim3(B_ * H_), blk, 0, stream>>>(Vw, sV);
    attn_topk_k<<<dim3(B_ * H_ * (S_ / QT_)), dim3(512), 0, stream>>>(Qhi, Qlo, Khi, Klo, Vw, sV, AO);
    gemm_f32_k<0><<<gg, blk, 0, stream>>>(AO, Wo, bo, out, nullptr, nullptr, 1.0f, B_ * S_, HID_, HID_);
}

// Round 7
// 1346.205 us; speedup vs baseline: 2.4855x; 1.0987x over previous
//
#include <hip/hip_runtime.h>
#include <math.h>

#define B_    2
#define S_    2048
#define HID_  1024
#define H_    16
#define D_    64
#define KEEP_ 204
#define QT_   8

typedef __attribute__((ext_vector_type(8))) short short8;
typedef __attribute__((ext_vector_type(4))) float f32x4;

// order-preserving fp32 -> uint32 mapping (larger float <=> larger uint)
__device__ __forceinline__ unsigned f2u_ord(float x) {
    unsigned b = __float_as_uint(x);
    return (b & 0x80000000u) ? ~b : (b | 0x80000000u);
}
__device__ __forceinline__ float u2f_ord(unsigned u) {
    unsigned b = (u & 0x80000000u) ? (u ^ 0x80000000u) : ~u;
    return __uint_as_float(b);
}
__device__ __forceinline__ float wave_sum(float x) {
    #pragma unroll
    for (int off = 32; off > 0; off >>= 1) x += __shfl_xor(x, off);
    return x;
}
__device__ __forceinline__ unsigned wave_max_u(unsigned x) {
    #pragma unroll
    for (int off = 32; off > 0; off >>= 1) {
        unsigned t = __shfl_xor(x, off);
        x = (t > x) ? t : x;
    }
    return x;
}
__device__ __forceinline__ unsigned short bf16rn(float x) {
    unsigned u = __float_as_uint(x);
    return (unsigned short)((u + 0x7fffu + ((u >> 16) & 1u)) >> 16);
}
__device__ __forceinline__ float bfhi2f(unsigned short h) {
    return __uint_as_float((unsigned)h << 16);
}

// ---------------- x (or any flat fp32 array) -> bf16 hi/lo ----------------
__global__ __launch_bounds__(256) void conv_x_k(
    const float* __restrict__ X,
    unsigned short* __restrict__ Xh, unsigned short* __restrict__ Xl)
{
    const int i = blockIdx.x * 256 + threadIdx.x;
    const float4 v = ((const float4*)X)[i];
    ushort4 h, l;
    h.x = bf16rn(v.x); l.x = bf16rn(v.x - bfhi2f(h.x));
    h.y = bf16rn(v.y); l.y = bf16rn(v.y - bfhi2f(h.y));
    h.z = bf16rn(v.z); l.z = bf16rn(v.z - bfhi2f(h.z));
    h.w = bf16rn(v.w); l.w = bf16rn(v.w - bfhi2f(h.w));
    ((ushort4*)Xh)[i] = h;
    ((ushort4*)Xl)[i] = l;
}

// ---------------- W [K][N] fp32 -> Wt [N][K] bf16 hi/lo (transpose) ----------------
__global__ __launch_bounds__(256) void conv_wT_k(
    const float* __restrict__ W,
    unsigned short* __restrict__ Wth, unsigned short* __restrict__ Wtl)
{
    __shared__ float t[64][65];
    const int k0 = blockIdx.y * 64, n0 = blockIdx.x * 64;
    const int r = threadIdx.x >> 4, c4 = (threadIdx.x & 15) * 4;
    #pragma unroll
    for (int i = 0; i < 4; i++) {
        const float4 v = *(const float4*)&W[(size_t)(k0 + r + 16 * i) * HID_ + n0 + c4];
        t[r + 16 * i][c4 + 0] = v.x;
        t[r + 16 * i][c4 + 1] = v.y;
        t[r + 16 * i][c4 + 2] = v.z;
        t[r + 16 * i][c4 + 3] = v.w;
    }
    __syncthreads();
    #pragma unroll
    for (int i = 0; i < 4; i++) {
        const int n = r + 16 * i;
        float a0 = t[c4 + 0][n], a1 = t[c4 + 1][n], a2 = t[c4 + 2][n], a3 = t[c4 + 3][n];
        ushort4 h, l;
        h.x = bf16rn(a0); l.x = bf16rn(a0 - bfhi2f(h.x));
        h.y = bf16rn(a1); l.y = bf16rn(a1 - bfhi2f(h.y));
        h.z = bf16rn(a2); l.z = bf16rn(a2 - bfhi2f(h.z));
        h.w = bf16rn(a3); l.w = bf16rn(a3 - bfhi2f(h.w));
        const size_t idx = (size_t)(n0 + n) * HID_ + k0 + c4;
        *(ushort4*)&Wth[idx] = h;
        *(ushort4*)&Wtl[idx] = l;
    }
}

// ---------------- split-bf16 MFMA GEMM: Y = A @ W + bias ----------------
// A: hi/lo bf16 [M][K] row-major. Wt: hi/lo bf16 [N][K] (transposed).
// 4 products (hh,hl,lh,ll) reproduce fp32 to ~1e-7 relative.
// Block = 256 thr = 4 waves; tile 64(m) x 128(n); wave = 32x64 (2x4 16x16 tiles).
// All mt/nt indices statically unrolled (R5 lesson: dynamic index -> scratch).
// MODE 0: fp32 Y[m*N+n]   MODE 1: fp32 heads   MODE 2: bf16 hi/lo heads, scaled
template <int MODE>
__global__ __launch_bounds__(256) void gemm_bf16_k(
    const unsigned short* __restrict__ Ah, const unsigned short* __restrict__ Al,
    const unsigned short* __restrict__ Bth, const unsigned short* __restrict__ Btl,
    const float* __restrict__ bias,
    float* __restrict__ Y, unsigned short* __restrict__ Yh, unsigned short* __restrict__ Yl,
    float scale)
{
    const int lane = threadIdx.x & 63;
    const int wv = threadIdx.x >> 6;
    const int m0 = blockIdx.y * 64 + (wv & 1) * 32;
    const int n0 = blockIdx.x * 128 + (wv >> 1) * 64;
    const int rl = lane & 15, quad = lane >> 4;

    f32x4 acc[2][4];
    #pragma unroll
    for (int mt = 0; mt < 2; mt++)
        #pragma unroll
        for (int nt = 0; nt < 4; nt++)
            acc[mt][nt] = (f32x4){0.f, 0.f, 0.f, 0.f};

    const size_t arow0 = (size_t)(m0 + rl) * HID_ + quad * 8;
    const size_t brow0 = (size_t)(n0 + rl) * HID_ + quad * 8;

    #pragma unroll 1
    for (int k0 = 0; k0 < HID_; k0 += 32) {
        short8 a_h[2], a_l[2], b_h[4], b_l[4];
        #pragma unroll
        for (int mt = 0; mt < 2; mt++) {
            a_h[mt] = *(const short8*)&Ah[arow0 + (size_t)mt * 16 * HID_ + k0];
            a_l[mt] = *(const short8*)&Al[arow0 + (size_t)mt * 16 * HID_ + k0];
        }
        #pragma unroll
        for (int nt = 0; nt < 4; nt++) {
            b_h[nt] = *(const short8*)&Bth[brow0 + (size_t)nt * 16 * HID_ + k0];
            b_l[nt] = *(const short8*)&Btl[brow0 + (size_t)nt * 16 * HID_ + k0];
        }
        #pragma unroll
        for (int mt = 0; mt < 2; mt++)
            #pragma unroll
            for (int nt = 0; nt < 4; nt++) {
                acc[mt][nt] = __builtin_amdgcn_mfma_f32_16x16x32_bf16(a_l[mt], b_l[nt], acc[mt][nt], 0, 0, 0);
                acc[mt][nt] = __builtin_amdgcn_mfma_f32_16x16x32_bf16(a_l[mt], b_h[nt], acc[mt][nt], 0, 0, 0);
                acc[mt][nt] = __builtin_amdgcn_mfma_f32_16x16x32_bf16(a_h[mt], b_l[nt], acc[mt][nt], 0, 0, 0);
                acc[mt][nt] = __builtin_amdgcn_mfma_f32_16x16x32_bf16(a_h[mt], b_h[nt], acc[mt][nt], 0, 0, 0);
            }
    }

    // epilogue: D[row = quad*4+reg][col = rl] per 16x16 tile
    #pragma unroll
    for (int nt = 0; nt < 4; nt++) {
        const int cn = n0 + nt * 16 + rl;
        const float bs = bias[cn];
        #pragma unroll
        for (int mt = 0; mt < 2; mt++) {
            #pragma unroll
            for (int reg = 0; reg < 4; reg++) {
                const int rm = m0 + mt * 16 + quad * 4 + reg;
                const float v = acc[mt][nt][reg] + bs;
                if (MODE == 0) {
                    Y[(size_t)rm * HID_ + cn] = v;
                } else if (MODE == 1) {
                    const int b = rm >> 11, s = rm & (S_ - 1);
                    const int h = cn >> 6, d = cn & 63;
                    Y[((size_t)(b * H_ + h) * S_ + s) * D_ + d] = v;
                } else {
                    const int b = rm >> 11, s = rm & (S_ - 1);
                    const int h = cn >> 6, d = cn & 63;
                    const float vs = v * scale;
                    const unsigned short hb = bf16rn(vs);
                    const unsigned short lb = bf16rn(vs - bfhi2f(hb));
                    const size_t idx = ((size_t)(b * H_ + h) * S_ + s) * D_ + d;
                    Yh[idx] = hb;
                    Yl[idx] = lb;
                }
            }
        }
    }
}

// ---------------- sumV[bh][d] = sum_j V[bh][j][d] ----------------
__global__ __launch_bounds__(256) void sumv_k(const float* __restrict__ V,
                                              float* __restrict__ sumV)
{
    const int bh = blockIdx.x;
    const int d = threadIdx.x & 63;
    const int g = threadIdx.x >> 6;
    float acc = 0.f;
    for (int j = g; j < S_; j += 4)
        acc += V[(bh * S_ + j) * D_ + d];
    __shared__ float part[4][D_];
    part[g][d] = acc;
    __syncthreads();
    if (threadIdx.x < 64)
        sumV[bh * D_ + d] = part[0][d] + part[1][d] + part[2][d] + part[3][d];
}

// ---------------- fused MFMA scores + exact top-204 + sparse-softmax AV ----------------
// 512 threads = 8 waves; ONE query row per wave. Writes AO as bf16 hi/lo
// (feeds the MFMA O-GEMM directly). 3 barriers total.
__global__ __launch_bounds__(512, 4) void attn_topk_k(
    const unsigned short* __restrict__ Qhi, const unsigned short* __restrict__ Qlo,
    const unsigned short* __restrict__ Khi, const unsigned short* __restrict__ Klo,
    const float* __restrict__ V, const float* __restrict__ sumV,
    unsigned short* __restrict__ AOh, unsigned short* __restrict__ AOl)
{
    const int tid = threadIdx.x;
    const int wv = tid >> 6;                  // 0..7 — this wave's query row
    const int lane = tid & 63;
    // XCD-locality remap: 4 bh per XCD -> K+V working set ~4 MB ~ one L2
    const int xcd = blockIdx.x & 7;
    const int w = blockIdx.x >> 3;
    const int bh = xcd * 4 + (w >> 8);
    const int q0 = (w & 255) * QT_;
    const int b = bh >> 4, h = bh & (H_ - 1);

    __shared__ __align__(16) float sc[QT_][S_];      // 64 KB; overlaid after extraction
    unsigned* hist_base = (unsigned*)&sc[0][0];
    int*      lj_base   = (int*)&sc[1][0];
    float*    lw_base   = (float*)&sc[2][0];

    const int mrow = lane & 15, quad = lane >> 4;

    // ---- A-fragments: Q hi/lo, rows duplicated (m&7) so no masking needed ----
    const size_t qrow = ((size_t)bh * S_ + q0 + (mrow & 7)) * D_;
    const short8 Ah0 = *(const short8*)&Qhi[qrow + quad * 8];
    const short8 Ah1 = *(const short8*)&Qhi[qrow + 32 + quad * 8];
    const short8 Al0 = *(const short8*)&Qlo[qrow + quad * 8];
    const short8 Al1 = *(const short8*)&Qlo[qrow + 32 + quad * 8];

    const size_t kbase = (size_t)bh * S_ * D_;

    // ---- scores: wave covers columns [wv*256, wv*256+256), all 8 rows ----
    {
        size_t koff = kbase + (size_t)(wv * 256 + mrow) * D_ + quad * 8;
        short8 Bh0 = *(const short8*)&Khi[koff];
        short8 Bh1 = *(const short8*)&Khi[koff + 32];
        short8 Bl0 = *(const short8*)&Klo[koff];
        short8 Bl1 = *(const short8*)&Klo[koff + 32];
        #pragma unroll 1
        for (int tl = 0; tl < 16; tl++) {
            short8 Ch0, Ch1, Cl0, Cl1;
            if (tl < 15) {
                const size_t k2 = koff + (size_t)16 * D_;
                Ch0 = *(const short8*)&Khi[k2];
                Ch1 = *(const short8*)&Khi[k2 + 32];
                Cl0 = *(const short8*)&Klo[k2];
                Cl1 = *(const short8*)&Klo[k2 + 32];
            }
            f32x4 acc0 = {0.f, 0.f, 0.f, 0.f};
            f32x4 acc1 = {0.f, 0.f, 0.f, 0.f};
            acc0 = __builtin_amdgcn_mfma_f32_16x16x32_bf16(Al0, Bl0, acc0, 0, 0, 0);
            acc1 = __builtin_amdgcn_mfma_f32_16x16x32_bf16(Al1, Bl1, acc1, 0, 0, 0);
            acc0 = __builtin_amdgcn_mfma_f32_16x16x32_bf16(Al0, Bh0, acc0, 0, 0, 0);
            acc1 = __builtin_amdgcn_mfma_f32_16x16x32_bf16(Al1, Bh1, acc1, 0, 0, 0);
            acc0 = __builtin_amdgcn_mfma_f32_16x16x32_bf16(Ah0, Bl0, acc0, 0, 0, 0);
            acc1 = __builtin_amdgcn_mfma_f32_16x16x32_bf16(Ah1, Bl1, acc1, 0, 0, 0);
            acc0 = __builtin_amdgcn_mfma_f32_16x16x32_bf16(Ah0, Bh0, acc0, 0, 0, 0);
            acc1 = __builtin_amdgcn_mfma_f32_16x16x32_bf16(Ah1, Bh1, acc1, 0, 0, 0);
            if (lane < 32) {   // C rows 0..7 live in lanes 0..31 (row=quad*4+reg, col=lane&15)
                const int colb = wv * 256 + tl * 16 + (lane & 15);
                #pragma unroll
                for (int reg = 0; reg < 4; reg++)
                    sc[quad * 4 + reg][colb] = acc0[reg] + acc1[reg];
            }
            Bh0 = Ch0; Bh1 = Ch1; Bl0 = Cl0; Bl1 = Cl1;
            koff += (size_t)16 * D_;
        }
    }
    __syncthreads();   // all strips written

    // ---- extract MY row into registers (static indices -> VGPRs) ----
    unsigned uu[32];   // element c <-> j = c*64 + lane
    #pragma unroll
    for (int c = 0; c < 32; c++)
        uu[c] = f2u_ord(sc[wv][c * 64 + lane]);
    __syncthreads();   // sc dead; overlays (hist/lists) may now be written

    unsigned* histw = hist_base + wv * 256;
    int*      lj    = lj_base + wv * 224;
    float*    lw    = lw_base + wv * 224;
    const float* Vb = V + kbase;

    // row max (ordered uints); sparse row includes zeros -> clamp to 0
    unsigned um = 0u;
    #pragma unroll
    for (int c = 0; c < 32; c++) { const unsigned t = uu[c]; um = (t > um) ? t : um; }
    um = wave_max_u(um);
    const float m = fmaxf(u2f_ord(um), 0.0f);

    // ---- exact radix select (wave-private, barrier-free) ----
    unsigned prefix = 0;
    int rem = KEEP_;
    #pragma unroll
    for (int pass = 3; pass >= 0; pass--) {
        const int shift = pass * 8;
        *(uint4*)&histw[lane * 4] = make_uint4(0u, 0u, 0u, 0u);
        #pragma unroll
        for (int c = 0; c < 32; c++) {
            const unsigned u = uu[c];
            const bool match = (pass == 3) ||
                ((u >> (shift + 8)) == (prefix >> (shift + 8)));
            if (match) atomicAdd(&histw[(u >> shift) & 255u], 1u);
        }
        const uint4 h4 = *(const uint4*)&histw[lane * 4];
        const unsigned s3 = h4.w;
        const unsigned s2 = h4.z + s3;
        const unsigned s1 = h4.y + s2;
        const unsigned s0 = h4.x + s1;
        unsigned incl = s0;                       // suffix scan across lanes
        #pragma unroll
        for (int off = 1; off < 64; off <<= 1) {
            const unsigned t = __shfl_down(incl, off);
            if (lane + off < 64) incl += t;
        }
        const unsigned excl = incl - s0;
        const unsigned cge[4] = {excl + s0, excl + s1, excl + s2, excl + s3};
        const unsigned cgt[4] = {excl + s1, excl + s2, excl + s3, excl};
        unsigned pk = 0;
        bool found = false;
        #pragma unroll
        for (int k = 0; k < 4; k++) {
            if (cge[k] >= (unsigned)rem && cgt[k] < (unsigned)rem) {
                found = true;
                pk = ((unsigned)(lane * 4 + k) << 16) | cgt[k];
            }
        }
        const unsigned long long fm = __ballot(found);
        const int src = __builtin_ctzll(fm);
        pk = __shfl(pk, src);
        prefix |= (pk >> 16) << shift;
        rem -= (int)(pk & 0xffffu);
    }
    const unsigned T = prefix;
    const float expT = __expf(u2f_ord(T) - m);
    const unsigned long long below = (1ULL << lane) - 1ULL;

    // ---- list build: all > T via ballot compaction ----
    float esum = 0.f;
    int base = 0;
    #pragma unroll
    for (int c = 0; c < 32; c++) {
        const unsigned u = uu[c];
        const bool gt = u > T;
        const unsigned long long mg = __ballot(gt);
        if (gt) {
            const int pos = base + (int)__popcll(mg & below);
            const float wgt = __expf(u2f_ord(u) - m);
            lj[pos] = c * 64 + lane;
            lw[pos] = wgt;
            esum += wgt;
        }
        base += (int)__popcll(mg);
    }
    // ---- ties: first `rem` in ascending j (jax stable tie-break) ----
    int need = rem;
    #pragma unroll
    for (int c = 0; c < 32; c++) {
        const unsigned u = uu[c];
        const bool eq = (u == T);
        const unsigned long long mg = __ballot(eq);
        if (eq) {
            const int pic = (int)__popcll(mg & below);
            if (pic < need) { lj[base + pic] = c * 64 + lane; lw[base + pic] = expT; }
        }
        const int cnt = (int)__popcll(mg);
        const int take = (cnt < need) ? cnt : need;
        base += take;
        need -= take;
    }
    const float E = wave_sum(esum) + (float)rem * expT;

    __asm__ volatile("s_waitcnt lgkmcnt(0)" ::: "memory");

    // ---- AV gather: lane = d, 8 loads in flight per batch ----
    float accW = 0.f, accS = 0.f;
    #pragma unroll 1
    for (int p = 0; p < 200; p += 8) {
        const int4   ja = *(const int4*)&lj[p];
        const int4   jb = *(const int4*)&lj[p + 4];
        const float4 wa = *(const float4*)&lw[p];
        const float4 wb = *(const float4*)&lw[p + 4];
        const float a0 = Vb[ja.x * 64 + lane];
        const float a1 = Vb[ja.y * 64 + lane];
        const float a2 = Vb[ja.z * 64 + lane];
        const float a3 = Vb[ja.w * 64 + lane];
        const float a4 = Vb[jb.x * 64 + lane];
        const float a5 = Vb[jb.y * 64 + lane];
        const float a6 = Vb[jb.z * 64 + lane];
        const float a7 = Vb[jb.w * 64 + lane];
        accW = fmaf(wa.x, a0, accW);
        accW = fmaf(wa.y, a1, accW);
        accW = fmaf(wa.z, a2, accW);
        accW = fmaf(wa.w, a3, accW);
        accW = fmaf(wb.x, a4, accW);
        accW = fmaf(wb.y, a5, accW);
        accW = fmaf(wb.z, a6, accW);
        accW = fmaf(wb.w, a7, accW);
        accS += a0 + a1 + a2 + a3 + a4 + a5 + a6 + a7;
    }
    {   // tail 200..203
        const int4   ja = *(const int4*)&lj[200];
        const float4 wa = *(const float4*)&lw[200];
        const float a0 = Vb[ja.x * 64 + lane];
        const float a1 = Vb[ja.y * 64 + lane];
        const float a2 = Vb[ja.z * 64 + lane];
        const float a3 = Vb[ja.w * 64 + lane];
        accW = fmaf(wa.x, a0, accW);
        accW = fmaf(wa.y, a1, accW);
        accW = fmaf(wa.z, a2, accW);
        accW = fmaf(wa.w, a3, accW);
        accS += a0 + a1 + a2 + a3;
    }
    const float em = __expf(-m);
    const float denom = E + (float)(S_ - KEEP_) * em;
    const float numer = accW + em * (sumV[bh * D_ + lane] - accS);
    const float v = numer / denom;
    const unsigned short hb = bf16rn(v);
    const unsigned short lb = bf16rn(v - bfhi2f(hb));
    const size_t oidx = ((size_t)(b * S_ + q0 + wv)) * HID_ + h * D_ + lane;
    AOh[oidx] = hb;
    AOl[oidx] = lb;
}

extern "C" void kernel_launch(void* const* d_in, const int* in_sizes, int n_in,
                              void* d_out, int out_size, void* d_ws, size_t ws_size,
                              hipStream_t stream) {
    const float* x  = (const float*)d_in[0];
    const float* Wq = (const float*)d_in[1];
    const float* bq = (const float*)d_in[2];
    const float* Wk = (const float*)d_in[3];
    const float* bk = (const float*)d_in[4];
    const float* Wv = (const float*)d_in[5];
    const float* bv = (const float*)d_in[6];
    const float* Wo = (const float*)d_in[7];
    const float* bo = (const float*)d_in[8];
    float* out = (float*)d_out;

    const size_t NQ = (size_t)B_ * H_ * S_ * D_;   // 4,194,304 elements
    const size_t NW = (size_t)HID_ * HID_;         // 1,048,576 elements
    unsigned short* p = (unsigned short*)d_ws;
    unsigned short* xh   = p; p += NQ;   // also AOh (x dead after V GEMM)
    unsigned short* xl   = p; p += NQ;   // also AOl
    unsigned short* Wt_h[4];
    unsigned short* Wt_l[4];
    for (int i = 0; i < 4; i++) { Wt_h[i] = p; p += NW; Wt_l[i] = p; p += NW; }
    unsigned short* Qhi = p; p += NQ;
    unsigned short* Qlo = p; p += NQ;
    unsigned short* Khi = p; p += NQ;
    unsigned short* Klo = p; p += NQ;
    float* Vw = (float*)p;
    float* sV = Vw + NQ;
    unsigned short* AOh = xh;
    unsigned short* AOl = xl;

    dim3 blk(256);
    conv_x_k<<<dim3(NQ / 1024), blk, 0, stream>>>(x, xh, xl);
    conv_wT_k<<<dim3(16, 16), blk, 0, stream>>>(Wq, Wt_h[0], Wt_l[0]);
    conv_wT_k<<<dim3(16, 16), blk, 0, stream>>>(Wk, Wt_h[1], Wt_l[1]);
    conv_wT_k<<<dim3(16, 16), blk, 0, stream>>>(Wv, Wt_h[2], Wt_l[2]);
    conv_wT_k<<<dim3(16, 16), blk, 0, stream>>>(Wo, Wt_h[3], Wt_l[3]);

    dim3 gg(HID_ / 128, (B_ * S_) / 64);
    gemm_bf16_k<2><<<gg, blk, 0, stream>>>(xh, xl, Wt_h[0], Wt_l[0], bq,
                                           nullptr, Qhi, Qlo, 0.125f);
    gemm_bf16_k<2><<<gg, blk, 0, stream>>>(xh, xl, Wt_h[1], Wt_l[1], bk,
                                           nullptr, Khi, Klo, 1.0f);
    gemm_bf16_k<1><<<gg, blk, 0, stream>>>(xh, xl, Wt_h[2], Wt_l[2], bv,
                                           Vw, nullptr, nullptr, 1.0f);
    sumv_k<<<dim3(B_ * H_), blk, 0, stream>>>(Vw, sV);
    attn_topk_k<<<dim3(B_ * H_ * (S_ / QT_)), dim3(512), 0, stream>>>(
        Qhi, Qlo, Khi, Klo, Vw, sV, AOh, AOl);
    gemm_bf16_k<0><<<gg, blk, 0, stream>>>(AOh, AOl, Wt_h[3], Wt_l[3], bo,
                                           out, nullptr, nullptr, 1.0f);
}

// Round 8
// 1249.581 us; speedup vs baseline: 2.6777x; 1.0773x over previous
//
#include <hip/hip_runtime.h>
#include <math.h>

#define B_    2
#define S_    2048
#define HID_  1024
#define H_    16
#define D_    64
#define KEEP_ 204
#define QT_   8

typedef __attribute__((ext_vector_type(8))) short short8;
typedef __attribute__((ext_vector_type(4))) float f32x4;

// order-preserving fp32 -> uint32 mapping (larger float <=> larger uint)
__device__ __forceinline__ unsigned f2u_ord(float x) {
    unsigned b = __float_as_uint(x);
    return (b & 0x80000000u) ? ~b : (b | 0x80000000u);
}
__device__ __forceinline__ float u2f_ord(unsigned u) {
    unsigned b = (u & 0x80000000u) ? (u ^ 0x80000000u) : ~u;
    return __uint_as_float(b);
}
__device__ __forceinline__ float wave_sum(float x) {
    #pragma unroll
    for (int off = 32; off > 0; off >>= 1) x += __shfl_xor(x, off);
    return x;
}
__device__ __forceinline__ unsigned wave_max_u(unsigned x) {
    #pragma unroll
    for (int off = 32; off > 0; off >>= 1) {
        unsigned t = __shfl_xor(x, off);
        x = (t > x) ? t : x;
    }
    return x;
}
__device__ __forceinline__ unsigned short bf16rn(float x) {
    unsigned u = __float_as_uint(x);
    return (unsigned short)((u + 0x7fffu + ((u >> 16) & 1u)) >> 16);
}
__device__ __forceinline__ float bfhi2f(unsigned short h) {
    return __uint_as_float((unsigned)h << 16);
}

// ---------------- x (flat fp32) -> bf16 hi/lo ----------------
__global__ __launch_bounds__(256) void conv_x_k(
    const float* __restrict__ X,
    unsigned short* __restrict__ Xh, unsigned short* __restrict__ Xl)
{
    const int i = blockIdx.x * 256 + threadIdx.x;
    const float4 v = ((const float4*)X)[i];
    ushort4 h, l;
    h.x = bf16rn(v.x); l.x = bf16rn(v.x - bfhi2f(h.x));
    h.y = bf16rn(v.y); l.y = bf16rn(v.y - bfhi2f(h.y));
    h.z = bf16rn(v.z); l.z = bf16rn(v.z - bfhi2f(h.z));
    h.w = bf16rn(v.w); l.w = bf16rn(v.w - bfhi2f(h.w));
    ((ushort4*)Xh)[i] = h;
    ((ushort4*)Xl)[i] = l;
}

// ---------------- W [K][N] fp32 -> Wt [N][K] bf16 hi/lo (transpose) ----------------
__global__ __launch_bounds__(256) void conv_wT_k(
    const float* __restrict__ W,
    unsigned short* __restrict__ Wth, unsigned short* __restrict__ Wtl)
{
    __shared__ float t[64][65];
    const int k0 = blockIdx.y * 64, n0 = blockIdx.x * 64;
    const int r = threadIdx.x >> 4, c4 = (threadIdx.x & 15) * 4;
    #pragma unroll
    for (int i = 0; i < 4; i++) {
        const float4 v = *(const float4*)&W[(size_t)(k0 + r + 16 * i) * HID_ + n0 + c4];
        t[r + 16 * i][c4 + 0] = v.x;
        t[r + 16 * i][c4 + 1] = v.y;
        t[r + 16 * i][c4 + 2] = v.z;
        t[r + 16 * i][c4 + 3] = v.w;
    }
    __syncthreads();
    #pragma unroll
    for (int i = 0; i < 4; i++) {
        const int n = r + 16 * i;
        float a0 = t[c4 + 0][n], a1 = t[c4 + 1][n], a2 = t[c4 + 2][n], a3 = t[c4 + 3][n];
        ushort4 h, l;
        h.x = bf16rn(a0); l.x = bf16rn(a0 - bfhi2f(h.x));
        h.y = bf16rn(a1); l.y = bf16rn(a1 - bfhi2f(h.y));
        h.z = bf16rn(a2); l.z = bf16rn(a2 - bfhi2f(h.z));
        h.w = bf16rn(a3); l.w = bf16rn(a3 - bfhi2f(h.w));
        const size_t idx = (size_t)(n0 + n) * HID_ + k0 + c4;
        *(ushort4*)&Wth[idx] = h;
        *(ushort4*)&Wtl[idx] = l;
    }
}

// ---------------- split-bf16 MFMA GEMM: Y = A @ W + bias ----------------
// unroll 2 on K so iter k+1's loads overlap iter k's MFMAs.
template <int MODE>
__global__ __launch_bounds__(256) void gemm_bf16_k(
    const unsigned short* __restrict__ Ah, const unsigned short* __restrict__ Al,
    const unsigned short* __restrict__ Bth, const unsigned short* __restrict__ Btl,
    const float* __restrict__ bias,
    float* __restrict__ Y, unsigned short* __restrict__ Yh, unsigned short* __restrict__ Yl,
    float scale)
{
    const int lane = threadIdx.x & 63;
    const int wv = threadIdx.x >> 6;
    const int m0 = blockIdx.y * 64 + (wv & 1) * 32;
    const int n0 = blockIdx.x * 128 + (wv >> 1) * 64;
    const int rl = lane & 15, quad = lane >> 4;

    f32x4 acc[2][4];
    #pragma unroll
    for (int mt = 0; mt < 2; mt++)
        #pragma unroll
        for (int nt = 0; nt < 4; nt++)
            acc[mt][nt] = (f32x4){0.f, 0.f, 0.f, 0.f};

    const size_t arow0 = (size_t)(m0 + rl) * HID_ + quad * 8;
    const size_t brow0 = (size_t)(n0 + rl) * HID_ + quad * 8;

    #pragma unroll 2
    for (int k0 = 0; k0 < HID_; k0 += 32) {
        short8 a_h[2], a_l[2], b_h[4], b_l[4];
        #pragma unroll
        for (int mt = 0; mt < 2; mt++) {
            a_h[mt] = *(const short8*)&Ah[arow0 + (size_t)mt * 16 * HID_ + k0];
            a_l[mt] = *(const short8*)&Al[arow0 + (size_t)mt * 16 * HID_ + k0];
        }
        #pragma unroll
        for (int nt = 0; nt < 4; nt++) {
            b_h[nt] = *(const short8*)&Bth[brow0 + (size_t)nt * 16 * HID_ + k0];
            b_l[nt] = *(const short8*)&Btl[brow0 + (size_t)nt * 16 * HID_ + k0];
        }
        #pragma unroll
        for (int mt = 0; mt < 2; mt++)
            #pragma unroll
            for (int nt = 0; nt < 4; nt++) {
                acc[mt][nt] = __builtin_amdgcn_mfma_f32_16x16x32_bf16(a_l[mt], b_l[nt], acc[mt][nt], 0, 0, 0);
                acc[mt][nt] = __builtin_amdgcn_mfma_f32_16x16x32_bf16(a_l[mt], b_h[nt], acc[mt][nt], 0, 0, 0);
                acc[mt][nt] = __builtin_amdgcn_mfma_f32_16x16x32_bf16(a_h[mt], b_l[nt], acc[mt][nt], 0, 0, 0);
                acc[mt][nt] = __builtin_amdgcn_mfma_f32_16x16x32_bf16(a_h[mt], b_h[nt], acc[mt][nt], 0, 0, 0);
            }
    }

    #pragma unroll
    for (int nt = 0; nt < 4; nt++) {
        const int cn = n0 + nt * 16 + rl;
        const float bs = bias[cn];
        #pragma unroll
        for (int mt = 0; mt < 2; mt++) {
            #pragma unroll
            for (int reg = 0; reg < 4; reg++) {
                const int rm = m0 + mt * 16 + quad * 4 + reg;
                const float v = acc[mt][nt][reg] + bs;
                if (MODE == 0) {
                    Y[(size_t)rm * HID_ + cn] = v;
                } else if (MODE == 1) {
                    const int b = rm >> 11, s = rm & (S_ - 1);
                    const int h = cn >> 6, d = cn & 63;
                    Y[((size_t)(b * H_ + h) * S_ + s) * D_ + d] = v;
                } else {
                    const int b = rm >> 11, s = rm & (S_ - 1);
                    const int h = cn >> 6, d = cn & 63;
                    const float vs = v * scale;
                    const unsigned short hb = bf16rn(vs);
                    const unsigned short lb = bf16rn(vs - bfhi2f(hb));
                    const size_t idx = ((size_t)(b * H_ + h) * S_ + s) * D_ + d;
                    Yh[idx] = hb;
                    Yl[idx] = lb;
                }
            }
        }
    }
}

// ---------------- sumV[bh][d] = sum_j V[bh][j][d] ----------------
__global__ __launch_bounds__(256) void sumv_k(const float* __restrict__ V,
                                              float* __restrict__ sumV)
{
    const int bh = blockIdx.x;
    const int d = threadIdx.x & 63;
    const int g = threadIdx.x >> 6;
    float acc = 0.f;
    for (int j = g; j < S_; j += 4)
        acc += V[(bh * S_ + j) * D_ + d];
    __shared__ float part[4][D_];
    part[g][d] = acc;
    __syncthreads();
    if (threadIdx.x < 64)
        sumV[bh * D_ + d] = part[0][d] + part[1][d] + part[2][d] + part[3][d];
}

// ---------------- fused MFMA scores + exact top-204 + sparse-softmax AV ----------------
// 512 threads = 8 waves; one query row per wave. Scores redistributed in TWO
// 32 KB rounds (r-loop fully unrolled -> uu[] indices static -> stays in VGPRs;
// the R5 spill came from a runtime first index, not chunking). LDS 32 KB +
// __launch_bounds__(512,6) (<=85 VGPR) -> 3 blocks/CU = 24 waves (was 16).
// Gather: two independent 8-load streams (16 loads in flight).
__global__ __launch_bounds__(512, 6) void attn_topk_k(
    const unsigned short* __restrict__ Qhi, const unsigned short* __restrict__ Qlo,
    const unsigned short* __restrict__ Khi, const unsigned short* __restrict__ Klo,
    const float* __restrict__ V, const float* __restrict__ sumV,
    unsigned short* __restrict__ AOh, unsigned short* __restrict__ AOl)
{
    const int tid = threadIdx.x;
    const int wv = tid >> 6;                  // 0..7 — this wave's query row
    const int lane = tid & 63;
    // XCD-locality remap: 4 bh per XCD -> K+V working set ~4 MB ~ one L2
    const int xcd = blockIdx.x & 7;
    const int w = blockIdx.x >> 3;
    const int bh = xcd * 4 + (w >> 8);
    const int q0 = (w & 255) * QT_;
    const int b = bh >> 4, h = bh & (H_ - 1);

    __shared__ __align__(16) float sc[QT_][1024];    // 32 KB; overlaid after extraction
    unsigned* hist_base = (unsigned*)&sc[0][0];      // 8x256 u32 = 8 KB (rows 0-1)
    int*      lj_base   = (int*)&sc[2][0];           // 8x224 int = 7 KB (rows 2-3)
    float*    lw_base   = (float*)&sc[4][0];         // 8x224 f32 (rows 4-5)

    const int mrow = lane & 15, quad = lane >> 4;

    // ---- A-fragments: Q hi/lo, rows duplicated (m&7) ----
    const size_t qrow = ((size_t)bh * S_ + q0 + (mrow & 7)) * D_;
    const short8 Ah0 = *(const short8*)&Qhi[qrow + quad * 8];
    const short8 Ah1 = *(const short8*)&Qhi[qrow + 32 + quad * 8];
    const short8 Al0 = *(const short8*)&Qlo[qrow + quad * 8];
    const short8 Al1 = *(const short8*)&Qlo[qrow + 32 + quad * 8];

    const size_t kbase = (size_t)bh * S_ * D_;
    unsigned uu[32];   // element cc <-> j = cc*64 + lane  (since r*1024 + c*64 = (r*16+c)*64)

    #pragma unroll
    for (int r = 0; r < 2; r++) {
        // ---- scores, round r: wave covers cols [r*1024 + wv*128, +128), all 8 rows ----
        size_t koff = kbase + (size_t)(r * 1024 + wv * 128 + mrow) * D_ + quad * 8;
        #pragma unroll 1
        for (int tl = 0; tl < 8; tl++) {
            const short8 Bh0 = *(const short8*)&Khi[koff];
            const short8 Bh1 = *(const short8*)&Khi[koff + 32];
            const short8 Bl0 = *(const short8*)&Klo[koff];
            const short8 Bl1 = *(const short8*)&Klo[koff + 32];
            f32x4 acc0 = {0.f, 0.f, 0.f, 0.f};
            f32x4 acc1 = {0.f, 0.f, 0.f, 0.f};
            acc0 = __builtin_amdgcn_mfma_f32_16x16x32_bf16(Al0, Bl0, acc0, 0, 0, 0);
            acc1 = __builtin_amdgcn_mfma_f32_16x16x32_bf16(Al1, Bl1, acc1, 0, 0, 0);
            acc0 = __builtin_amdgcn_mfma_f32_16x16x32_bf16(Al0, Bh0, acc0, 0, 0, 0);
            acc1 = __builtin_amdgcn_mfma_f32_16x16x32_bf16(Al1, Bh1, acc1, 0, 0, 0);
            acc0 = __builtin_amdgcn_mfma_f32_16x16x32_bf16(Ah0, Bl0, acc0, 0, 0, 0);
            acc1 = __builtin_amdgcn_mfma_f32_16x16x32_bf16(Ah1, Bl1, acc1, 0, 0, 0);
            acc0 = __builtin_amdgcn_mfma_f32_16x16x32_bf16(Ah0, Bh0, acc0, 0, 0, 0);
            acc1 = __builtin_amdgcn_mfma_f32_16x16x32_bf16(Ah1, Bh1, acc1, 0, 0, 0);
            if (lane < 32) {   // C rows 0..7 in lanes 0..31 (row=quad*4+reg, col=lane&15)
                const int colb = wv * 128 + tl * 16 + (lane & 15);
                #pragma unroll
                for (int reg = 0; reg < 4; reg++)
                    sc[quad * 4 + reg][colb] = acc0[reg] + acc1[reg];
            }
            koff += (size_t)16 * D_;
        }
        __syncthreads();   // round-r strips written
        #pragma unroll
        for (int c = 0; c < 16; c++)
            uu[r * 16 + c] = f2u_ord(sc[wv][c * 64 + lane]);
        __syncthreads();   // reads done; next round / overlays may write
    }

    unsigned* histw = hist_base + wv * 256;
    int*      lj    = lj_base + wv * 224;
    float*    lw    = lw_base + wv * 224;
    const float* Vb = V + kbase;

    // row max (ordered uints); sparse row includes zeros -> clamp to 0
    unsigned um = 0u;
    #pragma unroll
    for (int c = 0; c < 32; c++) { const unsigned t = uu[c]; um = (t > um) ? t : um; }
    um = wave_max_u(um);
    const float m = fmaxf(u2f_ord(um), 0.0f);

    // ---- exact radix select (wave-private, barrier-free) ----
    unsigned prefix = 0;
    int rem = KEEP_;
    #pragma unroll
    for (int pass = 3; pass >= 0; pass--) {
        const int shift = pass * 8;
        *(uint4*)&histw[lane * 4] = make_uint4(0u, 0u, 0u, 0u);
        #pragma unroll
        for (int c = 0; c < 32; c++) {
            const unsigned u = uu[c];
            const bool match = (pass == 3) ||
                ((u >> (shift + 8)) == (prefix >> (shift + 8)));
            if (match) atomicAdd(&histw[(u >> shift) & 255u], 1u);
        }
        const uint4 h4 = *(const uint4*)&histw[lane * 4];
        const unsigned s3 = h4.w;
        const unsigned s2 = h4.z + s3;
        const unsigned s1 = h4.y + s2;
        const unsigned s0 = h4.x + s1;
        unsigned incl = s0;                       // suffix scan across lanes
        #pragma unroll
        for (int off = 1; off < 64; off <<= 1) {
            const unsigned t = __shfl_down(incl, off);
            if (lane + off < 64) incl += t;
        }
        const unsigned excl = incl - s0;
        const unsigned cge[4] = {excl + s0, excl + s1, excl + s2, excl + s3};
        const unsigned cgt[4] = {excl + s1, excl + s2, excl + s3, excl};
        unsigned pk = 0;
        bool found = false;
        #pragma unroll
        for (int k = 0; k < 4; k++) {
            if (cge[k] >= (unsigned)rem && cgt[k] < (unsigned)rem) {
                found = true;
                pk = ((unsigned)(lane * 4 + k) << 16) | cgt[k];
            }
        }
        const unsigned long long fm = __ballot(found);
        const int src = __builtin_ctzll(fm);
        pk = __shfl(pk, src);
        prefix |= (pk >> 16) << shift;
        rem -= (int)(pk & 0xffffu);
    }
    const unsigned T = prefix;
    const float expT = __expf(u2f_ord(T) - m);
    const unsigned long long below = (1ULL << lane) - 1ULL;

    // ---- list build: all > T via ballot compaction ----
    float esum = 0.f;
    int base = 0;
    #pragma unroll
    for (int c = 0; c < 32; c++) {
        const unsigned u = uu[c];
        const bool gt = u > T;
        const unsigned long long mg = __ballot(gt);
        if (gt) {
            const int pos = base + (int)__popcll(mg & below);
            const float wgt = __expf(u2f_ord(u) - m);
            lj[pos] = c * 64 + lane;
            lw[pos] = wgt;
            esum += wgt;
        }
        base += (int)__popcll(mg);
    }
    // ---- ties: first `rem` in ascending j (jax stable tie-break) ----
    int need = rem;
    #pragma unroll
    for (int c = 0; c < 32; c++) {
        const unsigned u = uu[c];
        const bool eq = (u == T);
        const unsigned long long mg = __ballot(eq);
        if (eq) {
            const int pic = (int)__popcll(mg & below);
            if (pic < need) { lj[base + pic] = c * 64 + lane; lw[base + pic] = expT; }
        }
        const int cnt = (int)__popcll(mg);
        const int take = (cnt < need) ? cnt : need;
        base += take;
        need -= take;
    }
    const float E = wave_sum(esum) + (float)rem * expT;

    __asm__ volatile("s_waitcnt lgkmcnt(0)" ::: "memory");

    // ---- AV gather: lane = d, two independent streams (16 loads in flight) ----
    float accW = 0.f, accS = 0.f;
    float accW2 = 0.f, accS2 = 0.f;
    #pragma unroll 1
    for (int i = 0; i < 12; i++) {
        const int pA = i * 8, pB = 96 + i * 8;
        const int4   ja = *(const int4*)&lj[pA];
        const int4   jb = *(const int4*)&lj[pA + 4];
        const int4   jc = *(const int4*)&lj[pB];
        const int4   jd = *(const int4*)&lj[pB + 4];
        const float4 wa = *(const float4*)&lw[pA];
        const float4 wb = *(const float4*)&lw[pA + 4];
        const float4 wc = *(const float4*)&lw[pB];
        const float4 wd = *(const float4*)&lw[pB + 4];
        const float a0 = Vb[ja.x * 64 + lane];
        const float a1 = Vb[ja.y * 64 + lane];
        const float a2 = Vb[ja.z * 64 + lane];
        const float a3 = Vb[ja.w * 64 + lane];
        const float a4 = Vb[jb.x * 64 + lane];
        const float a5 = Vb[jb.y * 64 + lane];
        const float a6 = Vb[jb.z * 64 + lane];
        const float a7 = Vb[jb.w * 64 + lane];
        const float c0 = Vb[jc.x * 64 + lane];
        const float c1 = Vb[jc.y * 64 + lane];
        const float c2 = Vb[jc.z * 64 + lane];
        const float c3 = Vb[jc.w * 64 + lane];
        const float c4 = Vb[jd.x * 64 + lane];
        const float c5 = Vb[jd.y * 64 + lane];
        const float c6 = Vb[jd.z * 64 + lane];
        const float c7 = Vb[jd.w * 64 + lane];
        accW = fmaf(wa.x, a0, accW);  accW = fmaf(wa.y, a1, accW);
        accW = fmaf(wa.z, a2, accW);  accW = fmaf(wa.w, a3, accW);
        accW = fmaf(wb.x, a4, accW);  accW = fmaf(wb.y, a5, accW);
        accW = fmaf(wb.z, a6, accW);  accW = fmaf(wb.w, a7, accW);
        accW2 = fmaf(wc.x, c0, accW2); accW2 = fmaf(wc.y, c1, accW2);
        accW2 = fmaf(wc.z, c2, accW2); accW2 = fmaf(wc.w, c3, accW2);
        accW2 = fmaf(wd.x, c4, accW2); accW2 = fmaf(wd.y, c5, accW2);
        accW2 = fmaf(wd.z, c6, accW2); accW2 = fmaf(wd.w, c7, accW2);
        accS  += a0 + a1 + a2 + a3 + a4 + a5 + a6 + a7;
        accS2 += c0 + c1 + c2 + c3 + c4 + c5 + c6 + c7;
    }
    {   // tail 192..203 (12 elements)
        const int4   ja = *(const int4*)&lj[192];
        const int4   jb = *(const int4*)&lj[196];
        const int4   jc = *(const int4*)&lj[200];
        const float4 wa = *(const float4*)&lw[192];
        const float4 wb = *(const float4*)&lw[196];
        const float4 wc = *(const float4*)&lw[200];
        const float a0 = Vb[ja.x * 64 + lane];
        const float a1 = Vb[ja.y * 64 + lane];
        const float a2 = Vb[ja.z * 64 + lane];
        const float a3 = Vb[ja.w * 64 + lane];
        const float a4 = Vb[jb.x * 64 + lane];
        const float a5 = Vb[jb.y * 64 + lane];
        const float a6 = Vb[jb.z * 64 + lane];
        const float a7 = Vb[jb.w * 64 + lane];
        const float c0 = Vb[jc.x * 64 + lane];
        const float c1 = Vb[jc.y * 64 + lane];
        const float c2 = Vb[jc.z * 64 + lane];
        const float c3 = Vb[jc.w * 64 + lane];
        accW = fmaf(wa.x, a0, accW);  accW = fmaf(wa.y, a1, accW);
        accW = fmaf(wa.z, a2, accW);  accW = fmaf(wa.w, a3, accW);
        accW = fmaf(wb.x, a4, accW);  accW = fmaf(wb.y, a5, accW);
        accW = fmaf(wb.z, a6, accW);  accW = fmaf(wb.w, a7, accW);
        accW2 = fmaf(wc.x, c0, accW2); accW2 = fmaf(wc.y, c1, accW2);
        accW2 = fmaf(wc.z, c2, accW2); accW2 = fmaf(wc.w, c3, accW2);
        accS  += a0 + a1 + a2 + a3 + a4 + a5 + a6 + a7;
        accS2 += c0 + c1 + c2 + c3;
    }
    accW += accW2;
    accS += accS2;
    const float em = __expf(-m);
    const float denom = E + (float)(S_ - KEEP_) * em;
    const float numer = accW + em * (sumV[bh * D_ + lane] - accS);
    const float v = numer / denom;
    const unsigned short hb = bf16rn(v);
    const unsigned short lb = bf16rn(v - bfhi2f(hb));
    const size_t oidx = ((size_t)(b * S_ + q0 + wv)) * HID_ + h * D_ + lane;
    AOh[oidx] = hb;
    AOl[oidx] = lb;
}

extern "C" void kernel_launch(void* const* d_in, const int* in_sizes, int n_in,
                              void* d_out, int out_size, void* d_ws, size_t ws_size,
                              hipStream_t stream) {
    const float* x  = (const float*)d_in[0];
    const float* Wq = (const float*)d_in[1];
    const float* bq = (const float*)d_in[2];
    const float* Wk = (const float*)d_in[3];
    const float* bk = (const float*)d_in[4];
    const float* Wv = (const float*)d_in[5];
    const float* bv = (const float*)d_in[6];
    const float* Wo = (const float*)d_in[7];
    const float* bo = (const float*)d_in[8];
    float* out = (float*)d_out;

    const size_t NQ = (size_t)B_ * H_ * S_ * D_;   // 4,194,304 elements
    const size_t NW = (size_t)HID_ * HID_;         // 1,048,576 elements
    unsigned short* p = (unsigned short*)d_ws;
    unsigned short* xh   = p; p += NQ;   // also AOh (x dead after V GEMM)
    unsigned short* xl   = p; p += NQ;   // also AOl
    unsigned short* Wt_h[4];
    unsigned short* Wt_l[4];
    for (int i = 0; i < 4; i++) { Wt_h[i] = p; p += NW; Wt_l[i] = p; p += NW; }
    unsigned short* Qhi = p; p += NQ;
    unsigned short* Qlo = p; p += NQ;
    unsigned short* Khi = p; p += NQ;
    unsigned short* Klo = p; p += NQ;
    float* Vw = (float*)p;
    float* sV = Vw + NQ;
    unsigned short* AOh = xh;
    unsigned short* AOl = xl;

    dim3 blk(256);
    conv_x_k<<<dim3(NQ / 1024), blk, 0, stream>>>(x, xh, xl);
    conv_wT_k<<<dim3(16, 16), blk, 0, stream>>>(Wq, Wt_h[0], Wt_l[0]);
    conv_wT_k<<<dim3(16, 16), blk, 0, stream>>>(Wk, Wt_h[1], Wt_l[1]);
    conv_wT_k<<<dim3(16, 16), blk, 0, stream>>>(Wv, Wt_h[2], Wt_l[2]);
    conv_wT_k<<<dim3(16, 16), blk, 0, stream>>>(Wo, Wt_h[3], Wt_l[3]);

    dim3 gg(HID_ / 128, (B_ * S_) / 64);
    gemm_bf16_k<2><<<gg, blk, 0, stream>>>(xh, xl, Wt_h[0], Wt_l[0], bq,
                                           nullptr, Qhi, Qlo, 0.125f);
    gemm_bf16_k<2><<<gg, blk, 0, stream>>>(xh, xl, Wt_h[1], Wt_l[1], bk,
                                           nullptr, Khi, Klo, 1.0f);
    gemm_bf16_k<1><<<gg, blk, 0, stream>>>(xh, xl, Wt_h[2], Wt_l[2], bv,
                                           Vw, nullptr, nullptr, 1.0f);
    sumv_k<<<dim3(B_ * H_), blk, 0, stream>>>(Vw, sV);
    attn_topk_k<<<dim3(B_ * H_ * (S_ / QT_)), dim3(512), 0, stream>>>(
        Qhi, Qlo, Khi, Klo, Vw, sV, AOh, AOl);
    gemm_bf16_k<0><<<gg, blk, 0, stream>>>(AOh, AOl, Wt_h[3], Wt_l[3], bo,
                                           out, nullptr, nullptr, 1.0f);
}

// Round 9
// 1218.236 us; speedup vs baseline: 2.7466x; 1.0257x over previous
//
#include <hip/hip_runtime.h>
#include <math.h>

#define B_    2
#define S_    2048
#define HID_  1024
#define H_    16
#define D_    64
#define KEEP_ 204
#define QT_   8

typedef __attribute__((ext_vector_type(8))) short short8;
typedef __attribute__((ext_vector_type(4))) float f32x4;

// order-preserving fp32 -> uint32 mapping (larger float <=> larger uint)
__device__ __forceinline__ unsigned f2u_ord(float x) {
    unsigned b = __float_as_uint(x);
    return (b & 0x80000000u) ? ~b : (b | 0x80000000u);
}
__device__ __forceinline__ float u2f_ord(unsigned u) {
    unsigned b = (u & 0x80000000u) ? (u ^ 0x80000000u) : ~u;
    return __uint_as_float(b);
}
__device__ __forceinline__ float wave_sum(float x) {
    #pragma unroll
    for (int off = 32; off > 0; off >>= 1) x += __shfl_xor(x, off);
    return x;
}
__device__ __forceinline__ int wave_sum_i(int x) {
    #pragma unroll
    for (int off = 32; off > 0; off >>= 1) x += __shfl_xor(x, off);
    return x;
}
__device__ __forceinline__ unsigned wave_max_u(unsigned x) {
    #pragma unroll
    for (int off = 32; off > 0; off >>= 1) {
        unsigned t = __shfl_xor(x, off);
        x = (t > x) ? t : x;
    }
    return x;
}
__device__ __forceinline__ unsigned short bf16rn(float x) {
    unsigned u = __float_as_uint(x);
    return (unsigned short)((u + 0x7fffu + ((u >> 16) & 1u)) >> 16);
}
__device__ __forceinline__ float bfhi2f(unsigned short h) {
    return __uint_as_float((unsigned)h << 16);
}

// ---------------- x (flat fp32) -> bf16 hi/lo ----------------
__global__ __launch_bounds__(256) void conv_x_k(
    const float* __restrict__ X,
    unsigned short* __restrict__ Xh, unsigned short* __restrict__ Xl)
{
    const int i = blockIdx.x * 256 + threadIdx.x;
    const float4 v = ((const float4*)X)[i];
    ushort4 h, l;
    h.x = bf16rn(v.x); l.x = bf16rn(v.x - bfhi2f(h.x));
    h.y = bf16rn(v.y); l.y = bf16rn(v.y - bfhi2f(h.y));
    h.z = bf16rn(v.z); l.z = bf16rn(v.z - bfhi2f(h.z));
    h.w = bf16rn(v.w); l.w = bf16rn(v.w - bfhi2f(h.w));
    ((ushort4*)Xh)[i] = h;
    ((ushort4*)Xl)[i] = l;
}

// ---------------- W [K][N] fp32 -> Wt [N][K] bf16 hi/lo (transpose) ----------------
__global__ __launch_bounds__(256) void conv_wT_k(
    const float* __restrict__ W,
    unsigned short* __restrict__ Wth, unsigned short* __restrict__ Wtl)
{
    __shared__ float t[64][65];
    const int k0 = blockIdx.y * 64, n0 = blockIdx.x * 64;
    const int r = threadIdx.x >> 4, c4 = (threadIdx.x & 15) * 4;
    #pragma unroll
    for (int i = 0; i < 4; i++) {
        const float4 v = *(const float4*)&W[(size_t)(k0 + r + 16 * i) * HID_ + n0 + c4];
        t[r + 16 * i][c4 + 0] = v.x;
        t[r + 16 * i][c4 + 1] = v.y;
        t[r + 16 * i][c4 + 2] = v.z;
        t[r + 16 * i][c4 + 3] = v.w;
    }
    __syncthreads();
    #pragma unroll
    for (int i = 0; i < 4; i++) {
        const int n = r + 16 * i;
        float a0 = t[c4 + 0][n], a1 = t[c4 + 1][n], a2 = t[c4 + 2][n], a3 = t[c4 + 3][n];
        ushort4 h, l;
        h.x = bf16rn(a0); l.x = bf16rn(a0 - bfhi2f(h.x));
        h.y = bf16rn(a1); l.y = bf16rn(a1 - bfhi2f(h.y));
        h.z = bf16rn(a2); l.z = bf16rn(a2 - bfhi2f(h.z));
        h.w = bf16rn(a3); l.w = bf16rn(a3 - bfhi2f(h.w));
        const size_t idx = (size_t)(n0 + n) * HID_ + k0 + c4;
        *(ushort4*)&Wth[idx] = h;
        *(ushort4*)&Wtl[idx] = l;
    }
}

// ---------------- fused Q/K/V split-bf16 MFMA GEMM ----------------
// grid.z selects {Q (bf16 hi/lo, x1/8), K (bf16 hi/lo), V (bf16 single)}.
// One dispatch = 1536 blocks (3x occupancy of the separate version) + A reuse.
__global__ __launch_bounds__(256) void gemm_qkv_k(
    const unsigned short* __restrict__ Ah, const unsigned short* __restrict__ Al,
    const unsigned short* __restrict__ Bhq, const unsigned short* __restrict__ Blq,
    const unsigned short* __restrict__ Bhk, const unsigned short* __restrict__ Blk,
    const unsigned short* __restrict__ Bhv, const unsigned short* __restrict__ Blv,
    const float* __restrict__ bq, const float* __restrict__ bk, const float* __restrict__ bv,
    unsigned short* __restrict__ Qh, unsigned short* __restrict__ Ql,
    unsigned short* __restrict__ Kh, unsigned short* __restrict__ Kl,
    unsigned short* __restrict__ Vb16)
{
    const int z = blockIdx.z;
    const unsigned short* Bth = (z == 0) ? Bhq : (z == 1) ? Bhk : Bhv;
    const unsigned short* Btl = (z == 0) ? Blq : (z == 1) ? Blk : Blv;
    const float* bias = (z == 0) ? bq : (z == 1) ? bk : bv;

    const int lane = threadIdx.x & 63;
    const int wv = threadIdx.x >> 6;
    const int m0 = blockIdx.y * 64 + (wv & 1) * 32;
    const int n0 = blockIdx.x * 128 + (wv >> 1) * 64;
    const int rl = lane & 15, quad = lane >> 4;

    f32x4 acc[2][4];
    #pragma unroll
    for (int mt = 0; mt < 2; mt++)
        #pragma unroll
        for (int nt = 0; nt < 4; nt++)
            acc[mt][nt] = (f32x4){0.f, 0.f, 0.f, 0.f};

    const size_t arow0 = (size_t)(m0 + rl) * HID_ + quad * 8;
    const size_t brow0 = (size_t)(n0 + rl) * HID_ + quad * 8;

    #pragma unroll 2
    for (int k0 = 0; k0 < HID_; k0 += 32) {
        short8 a_h[2], a_l[2], b_h[4], b_l[4];
        #pragma unroll
        for (int mt = 0; mt < 2; mt++) {
            a_h[mt] = *(const short8*)&Ah[arow0 + (size_t)mt * 16 * HID_ + k0];
            a_l[mt] = *(const short8*)&Al[arow0 + (size_t)mt * 16 * HID_ + k0];
        }
        #pragma unroll
        for (int nt = 0; nt < 4; nt++) {
            b_h[nt] = *(const short8*)&Bth[brow0 + (size_t)nt * 16 * HID_ + k0];
            b_l[nt] = *(const short8*)&Btl[brow0 + (size_t)nt * 16 * HID_ + k0];
        }
        #pragma unroll
        for (int mt = 0; mt < 2; mt++)
            #pragma unroll
            for (int nt = 0; nt < 4; nt++) {
                acc[mt][nt] = __builtin_amdgcn_mfma_f32_16x16x32_bf16(a_l[mt], b_l[nt], acc[mt][nt], 0, 0, 0);
                acc[mt][nt] = __builtin_amdgcn_mfma_f32_16x16x32_bf16(a_l[mt], b_h[nt], acc[mt][nt], 0, 0, 0);
                acc[mt][nt] = __builtin_amdgcn_mfma_f32_16x16x32_bf16(a_h[mt], b_l[nt], acc[mt][nt], 0, 0, 0);
                acc[mt][nt] = __builtin_amdgcn_mfma_f32_16x16x32_bf16(a_h[mt], b_h[nt], acc[mt][nt], 0, 0, 0);
            }
    }

    const float scale = (z == 0) ? 0.125f : 1.0f;
    #pragma unroll
    for (int nt = 0; nt < 4; nt++) {
        const int cn = n0 + nt * 16 + rl;
        const float bs = bias[cn];
        const int h = cn >> 6, d = cn & 63;
        #pragma unroll
        for (int mt = 0; mt < 2; mt++) {
            #pragma unroll
            for (int reg = 0; reg < 4; reg++) {
                const int rm = m0 + mt * 16 + quad * 4 + reg;
                const int b = rm >> 11, s = rm & (S_ - 1);
                const float v = acc[mt][nt][reg] + bs;
                const size_t idx = ((size_t)(b * H_ + h) * S_ + s) * D_ + d;
                if (z == 2) {
                    Vb16[idx] = bf16rn(v);
                } else {
                    const float vs = v * scale;
                    const unsigned short hb = bf16rn(vs);
                    const unsigned short lb = bf16rn(vs - bfhi2f(hb));
                    if (z == 0) { Qh[idx] = hb; Ql[idx] = lb; }
                    else        { Kh[idx] = hb; Kl[idx] = lb; }
                }
            }
        }
    }
}

// ---------------- O-GEMM: out = AO @ Wo + bo (fp32 out) ----------------
__global__ __launch_bounds__(256) void gemm_o_k(
    const unsigned short* __restrict__ Ah, const unsigned short* __restrict__ Al,
    const unsigned short* __restrict__ Bth, const unsigned short* __restrict__ Btl,
    const float* __restrict__ bias, float* __restrict__ Y)
{
    const int lane = threadIdx.x & 63;
    const int wv = threadIdx.x >> 6;
    const int m0 = blockIdx.y * 64 + (wv & 1) * 32;
    const int n0 = blockIdx.x * 128 + (wv >> 1) * 64;
    const int rl = lane & 15, quad = lane >> 4;

    f32x4 acc[2][4];
    #pragma unroll
    for (int mt = 0; mt < 2; mt++)
        #pragma unroll
        for (int nt = 0; nt < 4; nt++)
            acc[mt][nt] = (f32x4){0.f, 0.f, 0.f, 0.f};

    const size_t arow0 = (size_t)(m0 + rl) * HID_ + quad * 8;
    const size_t brow0 = (size_t)(n0 + rl) * HID_ + quad * 8;

    #pragma unroll 2
    for (int k0 = 0; k0 < HID_; k0 += 32) {
        short8 a_h[2], a_l[2], b_h[4], b_l[4];
        #pragma unroll
        for (int mt = 0; mt < 2; mt++) {
            a_h[mt] = *(const short8*)&Ah[arow0 + (size_t)mt * 16 * HID_ + k0];
            a_l[mt] = *(const short8*)&Al[arow0 + (size_t)mt * 16 * HID_ + k0];
        }
        #pragma unroll
        for (int nt = 0; nt < 4; nt++) {
            b_h[nt] = *(const short8*)&Bth[brow0 + (size_t)nt * 16 * HID_ + k0];
            b_l[nt] = *(const short8*)&Btl[brow0 + (size_t)nt * 16 * HID_ + k0];
        }
        #pragma unroll
        for (int mt = 0; mt < 2; mt++)
            #pragma unroll
            for (int nt = 0; nt < 4; nt++) {
                acc[mt][nt] = __builtin_amdgcn_mfma_f32_16x16x32_bf16(a_l[mt], b_l[nt], acc[mt][nt], 0, 0, 0);
                acc[mt][nt] = __builtin_amdgcn_mfma_f32_16x16x32_bf16(a_l[mt], b_h[nt], acc[mt][nt], 0, 0, 0);
                acc[mt][nt] = __builtin_amdgcn_mfma_f32_16x16x32_bf16(a_h[mt], b_l[nt], acc[mt][nt], 0, 0, 0);
                acc[mt][nt] = __builtin_amdgcn_mfma_f32_16x16x32_bf16(a_h[mt], b_h[nt], acc[mt][nt], 0, 0, 0);
            }
    }

    #pragma unroll
    for (int nt = 0; nt < 4; nt++) {
        const int cn = n0 + nt * 16 + rl;
        const float bs = bias[cn];
        #pragma unroll
        for (int mt = 0; mt < 2; mt++)
            #pragma unroll
            for (int reg = 0; reg < 4; reg++) {
                const int rm = m0 + mt * 16 + quad * 4 + reg;
                Y[(size_t)rm * HID_ + cn] = acc[mt][nt][reg] + bs;
            }
    }
}

// ---------------- sumV[bh][d] = sum_j bf16(V)[bh][j][d]  (fp32 accumulate) ----------------
__global__ __launch_bounds__(256) void sumv_k(const unsigned short* __restrict__ Vb16,
                                              float* __restrict__ sumV)
{
    const int bh = blockIdx.x;
    const int d = threadIdx.x & 63;
    const int g = threadIdx.x >> 6;
    float acc = 0.f;
    for (int j = g; j < S_; j += 4)
        acc += bfhi2f(Vb16[((size_t)bh * S_ + j) * D_ + d]);
    __shared__ float part[4][D_];
    part[g][d] = acc;
    __syncthreads();
    if (threadIdx.x < 64)
        sumV[bh * D_ + d] = part[0][d] + part[1][d] + part[2][d] + part[3][d];
}

// ---------------- fused MFMA scores + exact top-204 + sparse-softmax AV ----------------
// 512 threads = 8 waves; one query row per wave. Exact threshold via 32-step
// radix-2 bit-descent (register compares + shuffle reduction) — NO LDS atomic
// histogram (R2-R8's 5.2e7 SQ_LDS_BANK_CONFLICT was same-address atomic
// serialization on the shared per-CU LDS pipe; occupancy couldn't hide it).
// V is bf16 (half gather traffic; sumV over the same bf16 values keeps the
// sparse-softmax identity exact).
__global__ __launch_bounds__(512, 6) void attn_topk_k(
    const unsigned short* __restrict__ Qhi, const unsigned short* __restrict__ Qlo,
    const unsigned short* __restrict__ Khi, const unsigned short* __restrict__ Klo,
    const unsigned short* __restrict__ Vb16, const float* __restrict__ sumV,
    unsigned short* __restrict__ AOh, unsigned short* __restrict__ AOl)
{
    const int tid = threadIdx.x;
    const int wv = tid >> 6;                  // 0..7 — this wave's query row
    const int lane = tid & 63;
    // XCD-locality remap: 4 bh per XCD -> K+V working set ~3 MB < one L2
    const int xcd = blockIdx.x & 7;
    const int w = blockIdx.x >> 3;
    const int bh = xcd * 4 + (w >> 8);
    const int q0 = (w & 255) * QT_;
    const int b = bh >> 4, h = bh & (H_ - 1);

    __shared__ __align__(16) float sc[QT_][1024];    // 32 KB; overlaid after extraction
    int*      lj_base   = (int*)&sc[2][0];           // 8x224 int (rows 2-3)
    float*    lw_base   = (float*)&sc[4][0];         // 8x224 f32 (rows 4-5)

    const int mrow = lane & 15, quad = lane >> 4;

    // ---- A-fragments: Q hi/lo, rows duplicated (m&7) ----
    const size_t qrow = ((size_t)bh * S_ + q0 + (mrow & 7)) * D_;
    const short8 Ah0 = *(const short8*)&Qhi[qrow + quad * 8];
    const short8 Ah1 = *(const short8*)&Qhi[qrow + 32 + quad * 8];
    const short8 Al0 = *(const short8*)&Qlo[qrow + quad * 8];
    const short8 Al1 = *(const short8*)&Qlo[qrow + 32 + quad * 8];

    const size_t kbase = (size_t)bh * S_ * D_;
    unsigned uu[32];   // element cc <-> j = cc*64 + lane

    #pragma unroll
    for (int r = 0; r < 2; r++) {
        // ---- scores, round r: wave covers cols [r*1024 + wv*128, +128), all 8 rows ----
        size_t koff = kbase + (size_t)(r * 1024 + wv * 128 + mrow) * D_ + quad * 8;
        #pragma unroll 1
        for (int tl = 0; tl < 8; tl++) {
            const short8 Bh0 = *(const short8*)&Khi[koff];
            const short8 Bh1 = *(const short8*)&Khi[koff + 32];
            const short8 Bl0 = *(const short8*)&Klo[koff];
            const short8 Bl1 = *(const short8*)&Klo[koff + 32];
            f32x4 acc0 = {0.f, 0.f, 0.f, 0.f};
            f32x4 acc1 = {0.f, 0.f, 0.f, 0.f};
            acc0 = __builtin_amdgcn_mfma_f32_16x16x32_bf16(Al0, Bl0, acc0, 0, 0, 0);
            acc1 = __builtin_amdgcn_mfma_f32_16x16x32_bf16(Al1, Bl1, acc1, 0, 0, 0);
            acc0 = __builtin_amdgcn_mfma_f32_16x16x32_bf16(Al0, Bh0, acc0, 0, 0, 0);
            acc1 = __builtin_amdgcn_mfma_f32_16x16x32_bf16(Al1, Bh1, acc1, 0, 0, 0);
            acc0 = __builtin_amdgcn_mfma_f32_16x16x32_bf16(Ah0, Bl0, acc0, 0, 0, 0);
            acc1 = __builtin_amdgcn_mfma_f32_16x16x32_bf16(Ah1, Bl1, acc1, 0, 0, 0);
            acc0 = __builtin_amdgcn_mfma_f32_16x16x32_bf16(Ah0, Bh0, acc0, 0, 0, 0);
            acc1 = __builtin_amdgcn_mfma_f32_16x16x32_bf16(Ah1, Bh1, acc1, 0, 0, 0);
            if (lane < 32) {   // C rows 0..7 in lanes 0..31 (row=quad*4+reg, col=lane&15)
                const int colb = wv * 128 + tl * 16 + (lane & 15);
                #pragma unroll
                for (int reg = 0; reg < 4; reg++)
                    sc[quad * 4 + reg][colb] = acc0[reg] + acc1[reg];
            }
            koff += (size_t)16 * D_;
        }
        __syncthreads();   // round-r strips written
        #pragma unroll
        for (int c = 0; c < 16; c++)
            uu[r * 16 + c] = f2u_ord(sc[wv][c * 64 + lane]);
        __syncthreads();   // reads done; next round / overlays may write
    }

    int*      lj    = lj_base + wv * 224;
    float*    lw    = lw_base + wv * 224;
    const unsigned short* Vb = Vb16 + kbase;

    // row max (ordered uints); sparse row includes zeros -> clamp to 0
    unsigned um = 0u;
    #pragma unroll
    for (int c = 0; c < 32; c++) { const unsigned t = uu[c]; um = (t > um) ? t : um; }
    um = wave_max_u(um);
    const float m = fmaxf(u2f_ord(um), 0.0f);

    // ---- exact threshold: radix-2 bit-descent, no LDS ----
    // After the loop, T = largest t with count(u >= t) >= KEEP_.
    unsigned p = 0;
    #pragma unroll 1
    for (int bit = 31; bit >= 0; bit--) {
        const unsigned trial = p | (1u << bit);
        if (trial > um) continue;          // count would be 0
        int c = 0;
        #pragma unroll
        for (int i = 0; i < 32; i++) c += (uu[i] >= trial) ? 1 : 0;
        c = wave_sum_i(c);
        if (c >= KEEP_) p = trial;
    }
    const unsigned T = p;
    int cgt = 0;
    #pragma unroll
    for (int i = 0; i < 32; i++) cgt += (uu[i] > T) ? 1 : 0;
    cgt = wave_sum_i(cgt);
    int rem = KEEP_ - cgt;                 // #ties to take (>= 1 by construction)

    const float expT = __expf(u2f_ord(T) - m);
    const unsigned long long below = (1ULL << lane) - 1ULL;

    // ---- list build: all > T via ballot compaction ----
    float esum = 0.f;
    int base = 0;
    #pragma unroll
    for (int c = 0; c < 32; c++) {
        const unsigned u = uu[c];
        const bool gt = u > T;
        const unsigned long long mg = __ballot(gt);
        if (gt) {
            const int pos = base + (int)__popcll(mg & below);
            const float wgt = __expf(u2f_ord(u) - m);
            lj[pos] = c * 64 + lane;
            lw[pos] = wgt;
            esum += wgt;
        }
        base += (int)__popcll(mg);
    }
    // ---- ties: first `rem` in ascending j (jax stable tie-break) ----
    int need = rem;
    #pragma unroll
    for (int c = 0; c < 32; c++) {
        const unsigned u = uu[c];
        const bool eq = (u == T);
        const unsigned long long mg = __ballot(eq);
        if (eq) {
            const int pic = (int)__popcll(mg & below);
            if (pic < need) { lj[base + pic] = c * 64 + lane; lw[base + pic] = expT; }
        }
        const int cnt = (int)__popcll(mg);
        const int take = (cnt < need) ? cnt : need;
        base += take;
        need -= take;
    }
    const float E = wave_sum(esum) + (float)rem * expT;

    __asm__ volatile("s_waitcnt lgkmcnt(0)" ::: "memory");

    // ---- AV gather (bf16 V): lane = d, two independent streams ----
    float accW = 0.f, accS = 0.f;
    float accW2 = 0.f, accS2 = 0.f;
    #pragma unroll 1
    for (int i = 0; i < 12; i++) {
        const int pA = i * 8, pB = 96 + i * 8;
        const int4   ja = *(const int4*)&lj[pA];
        const int4   jb = *(const int4*)&lj[pA + 4];
        const int4   jc = *(const int4*)&lj[pB];
        const int4   jd = *(const int4*)&lj[pB + 4];
        const float4 wa = *(const float4*)&lw[pA];
        const float4 wb = *(const float4*)&lw[pA + 4];
        const float4 wc = *(const float4*)&lw[pB];
        const float4 wd = *(const float4*)&lw[pB + 4];
        const float a0 = bfhi2f(Vb[ja.x * 64 + lane]);
        const float a1 = bfhi2f(Vb[ja.y * 64 + lane]);
        const float a2 = bfhi2f(Vb[ja.z * 64 + lane]);
        const float a3 = bfhi2f(Vb[ja.w * 64 + lane]);
        const float a4 = bfhi2f(Vb[jb.x * 64 + lane]);
        const float a5 = bfhi2f(Vb[jb.y * 64 + lane]);
        const float a6 = bfhi2f(Vb[jb.z * 64 + lane]);
        const float a7 = bfhi2f(Vb[jb.w * 64 + lane]);
        const float c0 = bfhi2f(Vb[jc.x * 64 + lane]);
        const float c1 = bfhi2f(Vb[jc.y * 64 + lane]);
        const float c2 = bfhi2f(Vb[jc.z * 64 + lane]);
        const float c3 = bfhi2f(Vb[jc.w * 64 + lane]);
        const float c4 = bfhi2f(Vb[jd.x * 64 + lane]);
        const float c5 = bfhi2f(Vb[jd.y * 64 + lane]);
        const float c6 = bfhi2f(Vb[jd.z * 64 + lane]);
        const float c7 = bfhi2f(Vb[jd.w * 64 + lane]);
        accW = fmaf(wa.x, a0, accW);  accW = fmaf(wa.y, a1, accW);
        accW = fmaf(wa.z, a2, accW);  accW = fmaf(wa.w, a3, accW);
        accW = fmaf(wb.x, a4, accW);  accW = fmaf(wb.y, a5, accW);
        accW = fmaf(wb.z, a6, accW);  accW = fmaf(wb.w, a7, accW);
        accW2 = fmaf(wc.x, c0, accW2); accW2 = fmaf(wc.y, c1, accW2);
        accW2 = fmaf(wc.z, c2, accW2); accW2 = fmaf(wc.w, c3, accW2);
        accW2 = fmaf(wd.x, c4, accW2); accW2 = fmaf(wd.y, c5, accW2);
        accW2 = fmaf(wd.z, c6, accW2); accW2 = fmaf(wd.w, c7, accW2);
        accS  += a0 + a1 + a2 + a3 + a4 + a5 + a6 + a7;
        accS2 += c0 + c1 + c2 + c3 + c4 + c5 + c6 + c7;
    }
    {   // tail 192..203 (12 elements)
        const int4   ja = *(const int4*)&lj[192];
        const int4   jb = *(const int4*)&lj[196];
        const int4   jc = *(const int4*)&lj[200];
        const float4 wa = *(const float4*)&lw[192];
        const float4 wb = *(const float4*)&lw[196];
        const float4 wc = *(const float4*)&lw[200];
        const float a0 = bfhi2f(Vb[ja.x * 64 + lane]);
        const float a1 = bfhi2f(Vb[ja.y * 64 + lane]);
        const float a2 = bfhi2f(Vb[ja.z * 64 + lane]);
        const float a3 = bfhi2f(Vb[ja.w * 64 + lane]);
        const float a4 = bfhi2f(Vb[jb.x * 64 + lane]);
        const float a5 = bfhi2f(Vb[jb.y * 64 + lane]);
        const float a6 = bfhi2f(Vb[jb.z * 64 + lane]);
        const float a7 = bfhi2f(Vb[jb.w * 64 + lane]);
        const float c0 = bfhi2f(Vb[jc.x * 64 + lane]);
        const float c1 = bfhi2f(Vb[jc.y * 64 + lane]);
        const float c2 = bfhi2f(Vb[jc.z * 64 + lane]);
        const float c3 = bfhi2f(Vb[jc.w * 64 + lane]);
        accW = fmaf(wa.x, a0, accW);  accW = fmaf(wa.y, a1, accW);
        accW = fmaf(wa.z, a2, accW);  accW = fmaf(wa.w, a3, accW);
        accW = fmaf(wb.x, a4, accW);  accW = fmaf(wb.y, a5, accW);
        accW = fmaf(wb.z, a6, accW);  accW = fmaf(wb.w, a7, accW);
        accW2 = fmaf(wc.x, c0, accW2); accW2 = fmaf(wc.y, c1, accW2);
        accW2 = fmaf(wc.z, c2, accW2); accW2 = fmaf(wc.w, c3, accW2);
        accS  += a0 + a1 + a2 + a3 + a4 + a5 + a6 + a7;
        accS2 += c0 + c1 + c2 + c3;
    }
    accW += accW2;
    accS += accS2;
    const float em = __expf(-m);
    const float denom = E + (float)(S_ - KEEP_) * em;
    const float numer = accW + em * (sumV[bh * D_ + lane] - accS);
    const float v = numer / denom;
    const unsigned short hb = bf16rn(v);
    const unsigned short lb = bf16rn(v - bfhi2f(hb));
    const size_t oidx = ((size_t)(b * S_ + q0 + wv)) * HID_ + h * D_ + lane;
    AOh[oidx] = hb;
    AOl[oidx] = lb;
}

extern "C" void kernel_launch(void* const* d_in, const int* in_sizes, int n_in,
                              void* d_out, int out_size, void* d_ws, size_t ws_size,
                              hipStream_t stream) {
    const float* x  = (const float*)d_in[0];
    const float* Wq = (const float*)d_in[1];
    const float* bq = (const float*)d_in[2];
    const float* Wk = (const float*)d_in[3];
    const float* bk = (const float*)d_in[4];
    const float* Wv = (const float*)d_in[5];
    const float* bv = (const float*)d_in[6];
    const float* Wo = (const float*)d_in[7];
    const float* bo = (const float*)d_in[8];
    float* out = (float*)d_out;

    const size_t NQ = (size_t)B_ * H_ * S_ * D_;   // 4,194,304 elements
    const size_t NW = (size_t)HID_ * HID_;         // 1,048,576 elements
    unsigned short* p = (unsigned short*)d_ws;
    unsigned short* xh   = p; p += NQ;   // also AOh (x dead after QKV GEMM)
    unsigned short* xl   = p; p += NQ;   // also AOl
    unsigned short* Wt_h[4];
    unsigned short* Wt_l[4];
    for (int i = 0; i < 4; i++) { Wt_h[i] = p; p += NW; Wt_l[i] = p; p += NW; }
    unsigned short* Qhi = p; p += NQ;
    unsigned short* Qlo = p; p += NQ;
    unsigned short* Khi = p; p += NQ;
    unsigned short* Klo = p; p += NQ;
    unsigned short* Vb16 = p; p += NQ;
    float* sV = (float*)p;               // B_*H_*D_ floats
    unsigned short* AOh = xh;
    unsigned short* AOl = xl;

    dim3 blk(256);
    conv_x_k<<<dim3(NQ / 1024), blk, 0, stream>>>(x, xh, xl);
    conv_wT_k<<<dim3(16, 16), blk, 0, stream>>>(Wq, Wt_h[0], Wt_l[0]);
    conv_wT_k<<<dim3(16, 16), blk, 0, stream>>>(Wk, Wt_h[1], Wt_l[1]);
    conv_wT_k<<<dim3(16, 16), blk, 0, stream>>>(Wv, Wt_h[2], Wt_l[2]);
    conv_wT_k<<<dim3(16, 16), blk, 0, stream>>>(Wo, Wt_h[3], Wt_l[3]);

    dim3 gqkv(HID_ / 128, (B_ * S_) / 64, 3);
    gemm_qkv_k<<<gqkv, blk, 0, stream>>>(xh, xl,
        Wt_h[0], Wt_l[0], Wt_h[1], Wt_l[1], Wt_h[2], Wt_l[2],
        bq, bk, bv, Qhi, Qlo, Khi, Klo, Vb16);
    sumv_k<<<dim3(B_ * H_), blk, 0, stream>>>(Vb16, sV);
    attn_topk_k<<<dim3(B_ * H_ * (S_ / QT_)), dim3(512), 0, stream>>>(
        Qhi, Qlo, Khi, Klo, Vb16, sV, AOh, AOl);
    dim3 go(HID_ / 128, (B_ * S_) / 64);
    gemm_o_k<<<go, blk, 0, stream>>>(AOh, AOl, Wt_h[3], Wt_l[3], bo, out);
}

// Round 10
// 1188.234 us; speedup vs baseline: 2.8159x; 1.0252x over previous
//
#include <hip/hip_runtime.h>
#include <math.h>

#define B_    2
#define S_    2048
#define HID_  1024
#define H_    16
#define D_    64
#define KEEP_ 204
#define QT_   8

typedef __attribute__((ext_vector_type(8))) short short8;
typedef __attribute__((ext_vector_type(4))) float f32x4;

// order-preserving fp32 -> uint32 mapping (larger float <=> larger uint)
__device__ __forceinline__ unsigned f2u_ord(float x) {
    unsigned b = __float_as_uint(x);
    return (b & 0x80000000u) ? ~b : (b | 0x80000000u);
}
__device__ __forceinline__ float u2f_ord(unsigned u) {
    unsigned b = (u & 0x80000000u) ? (u ^ 0x80000000u) : ~u;
    return __uint_as_float(b);
}
__device__ __forceinline__ float wave_sum(float x) {
    #pragma unroll
    for (int off = 32; off > 0; off >>= 1) x += __shfl_xor(x, off);
    return x;
}
__device__ __forceinline__ int wave_sum_i(int x) {
    #pragma unroll
    for (int off = 32; off > 0; off >>= 1) x += __shfl_xor(x, off);
    return x;
}
__device__ __forceinline__ unsigned wave_max_u(unsigned x) {
    #pragma unroll
    for (int off = 32; off > 0; off >>= 1) {
        unsigned t = __shfl_xor(x, off);
        x = (t > x) ? t : x;
    }
    return x;
}
__device__ __forceinline__ unsigned short bf16rn(float x) {
    unsigned u = __float_as_uint(x);
    return (unsigned short)((u + 0x7fffu + ((u >> 16) & 1u)) >> 16);
}
__device__ __forceinline__ float bfhi2f(unsigned short h) {
    return __uint_as_float((unsigned)h << 16);
}

// ---------------- x (flat fp32) -> bf16 hi/lo ----------------
__global__ __launch_bounds__(256) void conv_x_k(
    const float* __restrict__ X,
    unsigned short* __restrict__ Xh, unsigned short* __restrict__ Xl)
{
    const int i = blockIdx.x * 256 + threadIdx.x;
    const float4 v = ((const float4*)X)[i];
    ushort4 h, l;
    h.x = bf16rn(v.x); l.x = bf16rn(v.x - bfhi2f(h.x));
    h.y = bf16rn(v.y); l.y = bf16rn(v.y - bfhi2f(h.y));
    h.z = bf16rn(v.z); l.z = bf16rn(v.z - bfhi2f(h.z));
    h.w = bf16rn(v.w); l.w = bf16rn(v.w - bfhi2f(h.w));
    ((ushort4*)Xh)[i] = h;
    ((ushort4*)Xl)[i] = l;
}

// ---------------- W [K][N] fp32 -> Wt [N][K] bf16 hi/lo (transpose) ----------------
__global__ __launch_bounds__(256) void conv_wT_k(
    const float* __restrict__ W,
    unsigned short* __restrict__ Wth, unsigned short* __restrict__ Wtl)
{
    __shared__ float t[64][65];
    const int k0 = blockIdx.y * 64, n0 = blockIdx.x * 64;
    const int r = threadIdx.x >> 4, c4 = (threadIdx.x & 15) * 4;
    #pragma unroll
    for (int i = 0; i < 4; i++) {
        const float4 v = *(const float4*)&W[(size_t)(k0 + r + 16 * i) * HID_ + n0 + c4];
        t[r + 16 * i][c4 + 0] = v.x;
        t[r + 16 * i][c4 + 1] = v.y;
        t[r + 16 * i][c4 + 2] = v.z;
        t[r + 16 * i][c4 + 3] = v.w;
    }
    __syncthreads();
    #pragma unroll
    for (int i = 0; i < 4; i++) {
        const int n = r + 16 * i;
        float a0 = t[c4 + 0][n], a1 = t[c4 + 1][n], a2 = t[c4 + 2][n], a3 = t[c4 + 3][n];
        ushort4 h, l;
        h.x = bf16rn(a0); l.x = bf16rn(a0 - bfhi2f(h.x));
        h.y = bf16rn(a1); l.y = bf16rn(a1 - bfhi2f(h.y));
        h.z = bf16rn(a2); l.z = bf16rn(a2 - bfhi2f(h.z));
        h.w = bf16rn(a3); l.w = bf16rn(a3 - bfhi2f(h.w));
        const size_t idx = (size_t)(n0 + n) * HID_ + k0 + c4;
        *(ushort4*)&Wth[idx] = h;
        *(ushort4*)&Wtl[idx] = l;
    }
}

// ---------------- fused Q/K/V split-bf16 MFMA GEMM ----------------
// grid.z: 0=Q (hi/lo, x1/8), 1=K (hi/lo), 2=V -> TRANSPOSED bf16 Vt[bh][d][s]
__global__ __launch_bounds__(256) void gemm_qkv_k(
    const unsigned short* __restrict__ Ah, const unsigned short* __restrict__ Al,
    const unsigned short* __restrict__ Bhq, const unsigned short* __restrict__ Blq,
    const unsigned short* __restrict__ Bhk, const unsigned short* __restrict__ Blk,
    const unsigned short* __restrict__ Bhv, const unsigned short* __restrict__ Blv,
    const float* __restrict__ bq, const float* __restrict__ bk, const float* __restrict__ bv,
    unsigned short* __restrict__ Qh, unsigned short* __restrict__ Ql,
    unsigned short* __restrict__ Kh, unsigned short* __restrict__ Kl,
    unsigned short* __restrict__ Vt)
{
    const int z = blockIdx.z;
    const unsigned short* Bth = (z == 0) ? Bhq : (z == 1) ? Bhk : Bhv;
    const unsigned short* Btl = (z == 0) ? Blq : (z == 1) ? Blk : Blv;
    const float* bias = (z == 0) ? bq : (z == 1) ? bk : bv;

    const int lane = threadIdx.x & 63;
    const int wv = threadIdx.x >> 6;
    const int m0 = blockIdx.y * 64 + (wv & 1) * 32;
    const int n0 = blockIdx.x * 128 + (wv >> 1) * 64;
    const int rl = lane & 15, quad = lane >> 4;

    f32x4 acc[2][4];
    #pragma unroll
    for (int mt = 0; mt < 2; mt++)
        #pragma unroll
        for (int nt = 0; nt < 4; nt++)
            acc[mt][nt] = (f32x4){0.f, 0.f, 0.f, 0.f};

    const size_t arow0 = (size_t)(m0 + rl) * HID_ + quad * 8;
    const size_t brow0 = (size_t)(n0 + rl) * HID_ + quad * 8;

    #pragma unroll 2
    for (int k0 = 0; k0 < HID_; k0 += 32) {
        short8 a_h[2], a_l[2], b_h[4], b_l[4];
        #pragma unroll
        for (int mt = 0; mt < 2; mt++) {
            a_h[mt] = *(const short8*)&Ah[arow0 + (size_t)mt * 16 * HID_ + k0];
            a_l[mt] = *(const short8*)&Al[arow0 + (size_t)mt * 16 * HID_ + k0];
        }
        #pragma unroll
        for (int nt = 0; nt < 4; nt++) {
            b_h[nt] = *(const short8*)&Bth[brow0 + (size_t)nt * 16 * HID_ + k0];
            b_l[nt] = *(const short8*)&Btl[brow0 + (size_t)nt * 16 * HID_ + k0];
        }
        #pragma unroll
        for (int mt = 0; mt < 2; mt++)
            #pragma unroll
            for (int nt = 0; nt < 4; nt++) {
                acc[mt][nt] = __builtin_amdgcn_mfma_f32_16x16x32_bf16(a_l[mt], b_l[nt], acc[mt][nt], 0, 0, 0);
                acc[mt][nt] = __builtin_amdgcn_mfma_f32_16x16x32_bf16(a_l[mt], b_h[nt], acc[mt][nt], 0, 0, 0);
                acc[mt][nt] = __builtin_amdgcn_mfma_f32_16x16x32_bf16(a_h[mt], b_l[nt], acc[mt][nt], 0, 0, 0);
                acc[mt][nt] = __builtin_amdgcn_mfma_f32_16x16x32_bf16(a_h[mt], b_h[nt], acc[mt][nt], 0, 0, 0);
            }
    }

    const float scale = (z == 0) ? 0.125f : 1.0f;
    #pragma unroll
    for (int nt = 0; nt < 4; nt++) {
        const int cn = n0 + nt * 16 + rl;
        const float bs = bias[cn];
        const int h = cn >> 6, d = cn & 63;
        #pragma unroll
        for (int mt = 0; mt < 2; mt++) {
            #pragma unroll
            for (int reg = 0; reg < 4; reg++) {
                const int rm = m0 + mt * 16 + quad * 4 + reg;
                const int b = rm >> 11, s = rm & (S_ - 1);
                const float v = acc[mt][nt][reg] + bs;
                if (z == 2) {
                    // transposed: Vt[bh][d][s]
                    Vt[((size_t)(b * H_ + h) * D_ + d) * S_ + s] = bf16rn(v);
                } else {
                    const size_t idx = ((size_t)(b * H_ + h) * S_ + s) * D_ + d;
                    const float vs = v * scale;
                    const unsigned short hb = bf16rn(vs);
                    const unsigned short lb = bf16rn(vs - bfhi2f(hb));
                    if (z == 0) { Qh[idx] = hb; Ql[idx] = lb; }
                    else        { Kh[idx] = hb; Kl[idx] = lb; }
                }
            }
        }
    }
}

// ---------------- O-GEMM: out = AO @ Wo + bo (fp32 out) ----------------
__global__ __launch_bounds__(256) void gemm_o_k(
    const unsigned short* __restrict__ Ah, const unsigned short* __restrict__ Al,
    const unsigned short* __restrict__ Bth, const unsigned short* __restrict__ Btl,
    const float* __restrict__ bias, float* __restrict__ Y)
{
    const int lane = threadIdx.x & 63;
    const int wv = threadIdx.x >> 6;
    const int m0 = blockIdx.y * 64 + (wv & 1) * 32;
    const int n0 = blockIdx.x * 128 + (wv >> 1) * 64;
    const int rl = lane & 15, quad = lane >> 4;

    f32x4 acc[2][4];
    #pragma unroll
    for (int mt = 0; mt < 2; mt++)
        #pragma unroll
        for (int nt = 0; nt < 4; nt++)
            acc[mt][nt] = (f32x4){0.f, 0.f, 0.f, 0.f};

    const size_t arow0 = (size_t)(m0 + rl) * HID_ + quad * 8;
    const size_t brow0 = (size_t)(n0 + rl) * HID_ + quad * 8;

    #pragma unroll 2
    for (int k0 = 0; k0 < HID_; k0 += 32) {
        short8 a_h[2], a_l[2], b_h[4], b_l[4];
        #pragma unroll
        for (int mt = 0; mt < 2; mt++) {
            a_h[mt] = *(const short8*)&Ah[arow0 + (size_t)mt * 16 * HID_ + k0];
            a_l[mt] = *(const short8*)&Al[arow0 + (size_t)mt * 16 * HID_ + k0];
        }
        #pragma unroll
        for (int nt = 0; nt < 4; nt++) {
            b_h[nt] = *(const short8*)&Bth[brow0 + (size_t)nt * 16 * HID_ + k0];
            b_l[nt] = *(const short8*)&Btl[brow0 + (size_t)nt * 16 * HID_ + k0];
        }
        #pragma unroll
        for (int mt = 0; mt < 2; mt++)
            #pragma unroll
            for (int nt = 0; nt < 4; nt++) {
                acc[mt][nt] = __builtin_amdgcn_mfma_f32_16x16x32_bf16(a_l[mt], b_l[nt], acc[mt][nt], 0, 0, 0);
                acc[mt][nt] = __builtin_amdgcn_mfma_f32_16x16x32_bf16(a_l[mt], b_h[nt], acc[mt][nt], 0, 0, 0);
                acc[mt][nt] = __builtin_amdgcn_mfma_f32_16x16x32_bf16(a_h[mt], b_l[nt], acc[mt][nt], 0, 0, 0);
                acc[mt][nt] = __builtin_amdgcn_mfma_f32_16x16x32_bf16(a_h[mt], b_h[nt], acc[mt][nt], 0, 0, 0);
            }
    }

    #pragma unroll
    for (int nt = 0; nt < 4; nt++) {
        const int cn = n0 + nt * 16 + rl;
        const float bs = bias[cn];
        #pragma unroll
        for (int mt = 0; mt < 2; mt++)
            #pragma unroll
            for (int reg = 0; reg < 4; reg++) {
                const int rm = m0 + mt * 16 + quad * 4 + reg;
                Y[(size_t)rm * HID_ + cn] = acc[mt][nt][reg] + bs;
            }
    }
}

// ---------------- fused MFMA scores + exact top-204 + DENSE-MFMA sparse-softmax PV ----
// 512 threads = 8 waves, one query row per wave. After the exact bit-descent,
// each wave writes a dense bf16 weight row (selected -> exp(v-m), else e^-m;
// ties resolved exactly) into the dead score LDS, computes the denominator
// from the ACTUAL stored bf16 weights (num/denom consistent), and PV runs as
// 32 MFMAs/wave against transposed bf16 V. No list, no gather, no sumV.
#define WPAD_ 2056   // weight row stride (shorts): 4112 B -> rows 4 banks apart
__global__ __launch_bounds__(512, 6) void attn_topk_k(
    const unsigned short* __restrict__ Qhi, const unsigned short* __restrict__ Qlo,
    const unsigned short* __restrict__ Khi, const unsigned short* __restrict__ Klo,
    const unsigned short* __restrict__ Vt,
    unsigned short* __restrict__ AOh, unsigned short* __restrict__ AOl)
{
    const int tid = threadIdx.x;
    const int wv = tid >> 6;                  // 0..7 — this wave's query row
    const int lane = tid & 63;
    // XCD-locality remap: 4 bh per XCD -> K+Vt working set < one L2
    const int xcd = blockIdx.x & 7;
    const int w = blockIdx.x >> 3;
    const int bh = xcd * 4 + (w >> 8);
    const int q0 = (w & 255) * QT_;
    const int b = bh >> 4, h = bh & (H_ - 1);

    __shared__ __align__(16) unsigned char smem[8 * WPAD_ * 2 + 4096 + 64];
    float (*sc)[1024] = (float (*)[1024])smem;           // scores view (32 KB)
    unsigned short* w16 = (unsigned short*)smem;          // weights view [8][WPAD_]
    float* partial = (float*)(smem + 8 * WPAD_ * 2);      // [2][8][64]
    float* denomL  = (float*)(smem + 8 * WPAD_ * 2 + 4096); // [8]

    const int mrow = lane & 15, quad = lane >> 4;

    // ---- A-fragments: Q hi/lo, rows duplicated (m&7) ----
    const size_t qrow = ((size_t)bh * S_ + q0 + (mrow & 7)) * D_;
    const short8 Ah0 = *(const short8*)&Qhi[qrow + quad * 8];
    const short8 Ah1 = *(const short8*)&Qhi[qrow + 32 + quad * 8];
    const short8 Al0 = *(const short8*)&Qlo[qrow + quad * 8];
    const short8 Al1 = *(const short8*)&Qlo[qrow + 32 + quad * 8];

    const size_t kbase = (size_t)bh * S_ * D_;
    unsigned uu[32];   // slot cc <-> j = cc*64 + lane

    #pragma unroll
    for (int r = 0; r < 2; r++) {
        size_t koff = kbase + (size_t)(r * 1024 + wv * 128 + mrow) * D_ + quad * 8;
        #pragma unroll 1
        for (int tl = 0; tl < 8; tl++) {
            const short8 Bh0 = *(const short8*)&Khi[koff];
            const short8 Bh1 = *(const short8*)&Khi[koff + 32];
            const short8 Bl0 = *(const short8*)&Klo[koff];
            const short8 Bl1 = *(const short8*)&Klo[koff + 32];
            f32x4 acc0 = {0.f, 0.f, 0.f, 0.f};
            f32x4 acc1 = {0.f, 0.f, 0.f, 0.f};
            acc0 = __builtin_amdgcn_mfma_f32_16x16x32_bf16(Al0, Bl0, acc0, 0, 0, 0);
            acc1 = __builtin_amdgcn_mfma_f32_16x16x32_bf16(Al1, Bl1, acc1, 0, 0, 0);
            acc0 = __builtin_amdgcn_mfma_f32_16x16x32_bf16(Al0, Bh0, acc0, 0, 0, 0);
            acc1 = __builtin_amdgcn_mfma_f32_16x16x32_bf16(Al1, Bh1, acc1, 0, 0, 0);
            acc0 = __builtin_amdgcn_mfma_f32_16x16x32_bf16(Ah0, Bl0, acc0, 0, 0, 0);
            acc1 = __builtin_amdgcn_mfma_f32_16x16x32_bf16(Ah1, Bl1, acc1, 0, 0, 0);
            acc0 = __builtin_amdgcn_mfma_f32_16x16x32_bf16(Ah0, Bh0, acc0, 0, 0, 0);
            acc1 = __builtin_amdgcn_mfma_f32_16x16x32_bf16(Ah1, Bh1, acc1, 0, 0, 0);
            if (lane < 32) {   // C: row=quad*4+reg (0..7 in lanes 0..31), col=lane&15
                const int colb = wv * 128 + tl * 16 + (lane & 15);
                #pragma unroll
                for (int reg = 0; reg < 4; reg++)
                    sc[quad * 4 + reg][colb] = acc0[reg] + acc1[reg];
            }
            koff += (size_t)16 * D_;
        }
        __syncthreads();   // round-r strips written
        #pragma unroll
        for (int c = 0; c < 16; c++)
            uu[r * 16 + c] = f2u_ord(sc[wv][c * 64 + lane]);
        __syncthreads();   // reads done; next round may overwrite
    }

    // row max (ordered uints); sparse row includes zeros -> clamp to 0
    unsigned um = 0u;
    #pragma unroll
    for (int c = 0; c < 32; c++) { const unsigned t = uu[c]; um = (t > um) ? t : um; }
    um = wave_max_u(um);
    const float m = fmaxf(u2f_ord(um), 0.0f);
    const float em = __expf(-m);

    // ---- exact threshold: radix-2 bit-descent (registers + shuffles) ----
    unsigned p = 0;
    #pragma unroll 1
    for (int bit = 31; bit >= 0; bit--) {
        const unsigned trial = p | (1u << bit);
        if (trial > um) continue;
        int c = 0;
        #pragma unroll
        for (int i = 0; i < 32; i++) c += (uu[i] >= trial) ? 1 : 0;
        c = wave_sum_i(c);
        if (c >= KEEP_) p = trial;
    }
    const unsigned T = p;
    int cgt = 0;
    #pragma unroll
    for (int i = 0; i < 32; i++) cgt += (uu[i] > T) ? 1 : 0;
    cgt = wave_sum_i(cgt);
    const int rem = KEEP_ - cgt;           // #ties to take (>=1)

    // ---- exact tie selection: first `rem' ties in ascending j ----
    unsigned tieMask = 0;
    {
        const unsigned long long below = (1ULL << lane) - 1ULL;
        int need = rem;
        #pragma unroll
        for (int c = 0; c < 32; c++) {
            const bool eq = (uu[c] == T);
            const unsigned long long mg = __ballot(eq);
            if (eq && (int)__popcll(mg & below) < need) tieMask |= 1u << c;
            const int cnt = (int)__popcll(mg);
            need -= (cnt < need) ? cnt : need;
        }
    }

    // ---- dense bf16 weight row + denominator from stored weights ----
    float esum = 0.f;
    #pragma unroll
    for (int c = 0; c < 32; c++) {
        const unsigned u = uu[c];
        const bool sel = (u > T) || ((tieMask >> c) & 1u);
        const float wgt = sel ? __expf(u2f_ord(u) - m) : em;
        const unsigned short wb = bf16rn(wgt);
        esum += bfhi2f(wb);
        w16[wv * WPAD_ + c * 64 + lane] = wb;
    }
    const float denom = wave_sum(esum);
    if (lane == 0) denomL[wv] = denom;
    __syncthreads();   // weights + denoms visible to all waves

    // ---- PV via MFMA: wave = (n-tile = wv&3, K-half = wv>>2) ----
    {
        const int ntile = wv & 3;
        const int khalf = wv >> 2;
        const unsigned short* VtB =
            Vt + ((size_t)bh * D_ + ntile * 16 + mrow) * S_ + khalf * 1024 + quad * 8;
        const unsigned short* wrow = w16 + (mrow & 7) * WPAD_ + khalf * 1024 + quad * 8;
        f32x4 pacc = {0.f, 0.f, 0.f, 0.f};
        #pragma unroll 1
        for (int ch = 0; ch < 32; ch++) {
            const short8 aw = *(const short8*)&wrow[ch * 32];
            const short8 bv = *(const short8*)&VtB[ch * 32];
            pacc = __builtin_amdgcn_mfma_f32_16x16x32_bf16(aw, bv, pacc, 0, 0, 0);
        }
        if (quad < 2) {
            #pragma unroll
            for (int reg = 0; reg < 4; reg++)
                partial[(khalf * 8 + quad * 4 + reg) * 64 + ntile * 16 + mrow] = pacc[reg];
        }
    }
    __syncthreads();   // partials visible

    // ---- reduce K-halves, normalize, write AO (bf16 hi/lo) ----
    {
        const int q = tid >> 6;       // 0..7
        const int d = tid & 63;
        const float o = (partial[q * 64 + d] + partial[(8 + q) * 64 + d]) / denomL[q];
        const unsigned short hb = bf16rn(o);
        const unsigned short lb = bf16rn(o - bfhi2f(hb));
        const size_t oidx = ((size_t)(b * S_ + q0 + q)) * HID_ + h * D_ + d;
        AOh[oidx] = hb;
        AOl[oidx] = lb;
    }
}

extern "C" void kernel_launch(void* const* d_in, const int* in_sizes, int n_in,
                              void* d_out, int out_size, void* d_ws, size_t ws_size,
                              hipStream_t stream) {
    const float* x  = (const float*)d_in[0];
    const float* Wq = (const float*)d_in[1];
    const float* bq = (const float*)d_in[2];
    const float* Wk = (const float*)d_in[3];
    const float* bk = (const float*)d_in[4];
    const float* Wv = (const float*)d_in[5];
    const float* bv = (const float*)d_in[6];
    const float* Wo = (const float*)d_in[7];
    const float* bo = (const float*)d_in[8];
    float* out = (float*)d_out;

    const size_t NQ = (size_t)B_ * H_ * S_ * D_;   // 4,194,304 elements
    const size_t NW = (size_t)HID_ * HID_;         // 1,048,576 elements
    unsigned short* p = (unsigned short*)d_ws;
    unsigned short* xh   = p; p += NQ;   // also AOh (x dead after QKV GEMM)
    unsigned short* xl   = p; p += NQ;   // also AOl
    unsigned short* Wt_h[4];
    unsigned short* Wt_l[4];
    for (int i = 0; i < 4; i++) { Wt_h[i] = p; p += NW; Wt_l[i] = p; p += NW; }
    unsigned short* Qhi = p; p += NQ;
    unsigned short* Qlo = p; p += NQ;
    unsigned short* Khi = p; p += NQ;
    unsigned short* Klo = p; p += NQ;
    unsigned short* Vt  = p; p += NQ;
    unsigned short* AOh = xh;
    unsigned short* AOl = xl;

    dim3 blk(256);
    conv_x_k<<<dim3(NQ / 1024), blk, 0, stream>>>(x, xh, xl);
    conv_wT_k<<<dim3(16, 16), blk, 0, stream>>>(Wq, Wt_h[0], Wt_l[0]);
    conv_wT_k<<<dim3(16, 16), blk, 0, stream>>>(Wk, Wt_h[1], Wt_l[1]);
    conv_wT_k<<<dim3(16, 16), blk, 0, stream>>>(Wv, Wt_h[2], Wt_l[2]);
    conv_wT_k<<<dim3(16, 16), blk, 0, stream>>>(Wo, Wt_h[3], Wt_l[3]);

    dim3 gqkv(HID_ / 128, (B_ * S_) / 64, 3);
    gemm_qkv_k<<<gqkv, blk, 0, stream>>>(xh, xl,
        Wt_h[0], Wt_l[0], Wt_h[1], Wt_l[1], Wt_h[2], Wt_l[2],
        bq, bk, bv, Qhi, Qlo, Khi, Klo, Vt);
    attn_topk_k<<<dim3(B_ * H_ * (S_ / QT_)), dim3(512), 0, stream>>>(
        Qhi, Qlo, Khi, Klo, Vt, AOh, AOl);
    dim3 go(HID_ / 128, (B_ * S_) / 64);
    gemm_o_k<<<go, blk, 0, stream>>>(AOh, AOl, Wt_h[3], Wt_l[3], bo, out);
}